// Round 8
// baseline (1630.634 us; speedup 1.0000x reference)
//
#include <hip/hip_runtime.h>

#define N_NODES 50000
#define N_FEAT  128
#define HID     64
#define N_EDGES 1600000
#define LN_EPS  1e-5f
#define NB2     400          // bins per side
#define BW2     125          // nodes per bin (400*125 = 50000)
#define CAP2    5120u        // per-bin record capacity (mean 4000, +17 sigma)

typedef unsigned int uint;

__device__ __forceinline__ float bcastf(float v, int l){
  return __uint_as_float(__builtin_amdgcn_readlane(__float_as_uint(v), l));
}
__device__ __forceinline__ unsigned short f2bf(float f){
  unsigned u = __float_as_uint(f);
  unsigned r = (u + 0x7fff + ((u >> 16) & 1)) >> 16;
  return (unsigned short)r;
}
__device__ __forceinline__ float bf2f(unsigned short u){
  return __uint_as_float(((unsigned)u) << 16);
}
// unscaled u8 accumulate (2 VALU/elem: cvt + add); bias 128 corrected once per node
__device__ __forceinline__ void accu8(float* a, uint2 v){
  a[0] += (float)( v.x         & 0xffu);
  a[1] += (float)((v.x >> 8)   & 0xffu);
  a[2] += (float)((v.x >> 16)  & 0xffu);
  a[3] += (float)( v.x >> 24         );
  a[4] += (float)( v.y         & 0xffu);
  a[5] += (float)((v.y >> 8)   & 0xffu);
  a[6] += (float)((v.y >> 16)  & 0xffu);
  a[7] += (float)( v.y >> 24         );
}

// ---------------- precompute: Wc = Wpsi @ W, bc = combined bias, pad rows = 128 ---------
__global__ void prep_kernel(const float* __restrict__ Wpp, const float* __restrict__ Wp,
                            const float* __restrict__ Wpn, const float* __restrict__ Wn,
                            const float* __restrict__ bp, const float* __restrict__ bpp,
                            const float* __restrict__ bn, const float* __restrict__ bpn,
                            float* __restrict__ Wc_p, float* __restrict__ Wc_n,
                            float* __restrict__ bc,
                            unsigned char* __restrict__ xq_p, unsigned char* __restrict__ xq_n){
  int idx = blockIdx.x * blockDim.x + threadIdx.x;
  if (idx < 4096){
    int j = idx >> 6, k = idx & 63;
    float sp = 0.f, sn = 0.f;
    for (int m = 0; m < 64; ++m){
      sp += Wpp[j * 64 + m] * Wp[m * 64 + k];
      sn += Wpn[j * 64 + m] * Wn[m * 64 + k];
    }
    Wc_p[idx] = sp; Wc_n[idx] = sn;
  } else if (idx < 4160){
    int j = idx - 4096;
    float s = bpp[j] + bpn[j];
    for (int m = 0; m < 64; ++m) s += Wpp[j * 64 + m] * bp[m] + Wpn[j * 64 + m] * bn[m];
    bc[j] = s;
  } else if (idx < 4224){
    // pad row decodes to exactly 0: byte 128 with bias-128 correction
    xq_p[(size_t)N_NODES * 64 + (idx - 4160)] = 128;
    xq_n[(size_t)N_NODES * 64 + (idx - 4160)] = 128;
  }
}

// ---------------- phase A: bin edges by dst range (400 bins/side) ----------------
__global__ __launch_bounds__(256) void binA_kernel(
    const int* __restrict__ ep, const int* __restrict__ en,
    uint* __restrict__ bin_cur, uint* __restrict__ recs_p, uint* __restrict__ recs_n){
  __shared__ uint sh[8192];
  __shared__ uint cnt2[NB2], gb2[NB2], rnk2[NB2];
  const int NBLK = (N_EDGES + 8191) / 8192;
  int bid = blockIdx.x;
  int side = bid >= NBLK;
  const int* e = side ? en : ep;
  uint* recs = side ? recs_n : recs_p;
  uint* bcur = bin_cur + side * NB2;
  int cbase = (side ? bid - NBLK : bid) * 8192;
  int tid = threadIdx.x;
  for (int i = tid; i < NB2; i += 256){ cnt2[i] = 0; rnk2[i] = 0; }
  __syncthreads();
  for (int i = tid; i < 8192; i += 256){
    int t = cbase + i;
    uint r = 0xFFFFFFFFu;
    if (t < N_EDGES){
      uint s = (uint)e[t], d = (uint)e[N_EDGES + t];
      r = (d << 16) | s;
      atomicAdd(&cnt2[d / BW2], 1u);
    }
    sh[i] = r;
  }
  __syncthreads();
  for (int i = tid; i < NB2; i += 256) gb2[i] = atomicAdd(&bcur[i], cnt2[i]);
  __syncthreads();
  for (int i = tid; i < 8192; i += 256){
    uint r = sh[i];
    if (r != 0xFFFFFFFFu){
      uint b = (r >> 16) / BW2;
      uint pos = gb2[b] + atomicAdd(&rnk2[b], 1u);
      recs[b * CAP2 + pos] = r;
    }
  }
}

// -------- LDS counting sort per bin: dinv, off (global CSR offsets), cs (coalesced) ------
__global__ __launch_bounds__(256) void fillC_kernel(
    const uint* __restrict__ bin_cur,
    const uint* __restrict__ recs_p, const uint* __restrict__ recs_n,
    int* __restrict__ off_p, int* __restrict__ off_n,
    float* __restrict__ dinv_p, float* __restrict__ dinv_n,
    unsigned short* __restrict__ cs_p, unsigned short* __restrict__ cs_n){
  __shared__ int hist[128];
  __shared__ int curx[128];
  __shared__ unsigned short staged[CAP2];
  __shared__ uint base_s;
  int bid = blockIdx.x;
  int side = bid >= NB2; int b = side ? bid - NB2 : bid;
  const uint* recs = (side ? recs_n : recs_p) + (size_t)b * CAP2;
  int* off = side ? off_n : off_p;
  float* dinv = side ? dinv_n : dinv_p;
  unsigned short* cs = side ? cs_n : cs_p;
  int tid = threadIdx.x, lane = tid & 63, wid = tid >> 6;
  int nodebase = b * BW2;
  if (tid < 128) hist[tid] = 0;
  __syncthreads();
  uint n = bin_cur[side * NB2 + b];
  if (wid == 1){                        // bin's global output base
    uint s = 0;
    for (int k = lane; k < b; k += 64) s += bin_cur[side * NB2 + k];
    #pragma unroll
    for (int d = 1; d < 64; d <<= 1) s += __shfl_xor(s, d);
    if (lane == 0) base_s = s;
  }
  for (uint i = tid; i < n; i += 256)
    atomicAdd(&hist[(recs[i] >> 16) - nodebase], 1);
  __syncthreads();
  if (tid < BW2)
    dinv[nodebase + tid] = rsqrtf((float)(hist[tid] + 1));
  if (wid == 0){                        // exclusive scan hist -> curx
    int carry = 0;
    #pragma unroll
    for (int base = 0; base < BW2; base += 64){
      int idx = base + lane;
      int v = (idx < BW2) ? hist[idx] : 0;
      int x = v;
      #pragma unroll
      for (int d = 1; d < 64; d <<= 1){
        int y = __shfl_up(x, d);
        if (lane >= d) x += y;
      }
      if (idx < BW2) curx[idx] = carry + x - v;
      int tot = __shfl(x, 63);
      carry = carry + tot;
    }
  }
  __syncthreads();
  if (tid < BW2) off[nodebase + tid] = (int)base_s + curx[tid];
  if (b == NB2 - 1 && tid == 0) off[N_NODES] = (int)(base_s + n);
  __syncthreads();
  for (uint i = tid; i < n; i += 256){
    uint r = recs[i];
    int d = (int)(r >> 16) - nodebase;
    int p = atomicAdd(&curx[d], 1);
    staged[p] = (unsigned short)(r & 0xFFFFu);
  }
  __syncthreads();
  uint base = base_s;
  for (uint i = tid; i < n; i += 256) cs[base + i] = staged[i];
}

// ---------------- encoder: hbase = x@Wenc^T+b; hn = LN(hbase). Weights in VGPRs ----------
// launch_bounds(256, 2): pin >=256 VGPR budget so we[128] stays in registers (R7: spill!)
__global__ __launch_bounds__(256, 2) void enc_kernel(
    const float* __restrict__ x, const float* __restrict__ Wenc, const float* __restrict__ benc,
    const float* __restrict__ gamma, const float* __restrict__ beta,
    float* __restrict__ hbase, float* __restrict__ hn){
  int lane = threadIdx.x & 63, wid = threadIdx.x >> 6;
  float we[128];
  const float* wr = Wenc + lane * N_FEAT;
  #pragma unroll
  for (int k4 = 0; k4 < 32; ++k4){
    float4 v = *(const float4*)(wr + 4 * k4);
    we[4*k4] = v.x; we[4*k4+1] = v.y; we[4*k4+2] = v.z; we[4*k4+3] = v.w;
  }
  float bv = benc[lane], g = gamma[lane], bt = beta[lane];
  int gw = blockIdx.x * 4 + wid, nw = gridDim.x * 4;
  for (int p = gw; p < N_NODES / 2; p += nw){
    int n0 = 2 * p, n1 = n0 + 1;
    float xa0 = x[(size_t)n0 * N_FEAT + lane], xb0 = x[(size_t)n0 * N_FEAT + 64 + lane];
    float xa1 = x[(size_t)n1 * N_FEAT + lane], xb1 = x[(size_t)n1 * N_FEAT + 64 + lane];
    float h0 = bv, h1 = bv;
    #pragma unroll
    for (int k = 0; k < 64; ++k){
      h0 += bcastf(xa0, k) * we[k];
      h1 += bcastf(xa1, k) * we[k];
      h0 += bcastf(xb0, k) * we[64 + k];
      h1 += bcastf(xb1, k) * we[64 + k];
    }
    hbase[n0 * HID + lane] = h0;
    hbase[n1 * HID + lane] = h1;
    float s0 = h0, q0 = h0 * h0, s1 = h1, q1 = h1 * h1;
    #pragma unroll
    for (int d = 1; d < 64; d <<= 1){
      s0 += __shfl_xor(s0, d); q0 += __shfl_xor(q0, d);
      s1 += __shfl_xor(s1, d); q1 += __shfl_xor(q1, d);
    }
    float mu0 = s0 * (1.0f/64.0f), var0 = q0 * (1.0f/64.0f) - mu0 * mu0;
    float mu1 = s1 * (1.0f/64.0f), var1 = q1 * (1.0f/64.0f) - mu1 * mu1;
    hn[n0 * HID + lane] = (h0 - mu0) * rsqrtf(var0 + LN_EPS) * g + bt;
    hn[n1 * HID + lane] = (h1 - mu1) * rsqrtf(var1 + LN_EPS) * g + bt;
  }
}

// -------- convA: GEMV (VGPR weights) -> bf16 temp; per-feature colmax via atomicMax ------
// launch_bounds(256, 2): pin >=256 VGPR budget so wp[64]+wn[64] stay in registers.
// R7 shipped without this: compiler chose 84 VGPRs, spilled both arrays to scratch,
// convA went 30 -> 99 us (VALUBusy 16%). Do not remove.
__global__ __launch_bounds__(256, 2) void convA_kernel(
    const float* __restrict__ hn, const float* __restrict__ Wc_p, const float* __restrict__ Wc_n,
    const float* __restrict__ dinv_p, const float* __restrict__ dinv_n,
    unsigned short* __restrict__ tmp_p, unsigned short* __restrict__ tmp_n,
    uint* __restrict__ colmax){
  int lane = threadIdx.x & 63, wid = threadIdx.x >> 6;
  float wp[64], wn[64];
  const float* wpr = Wc_p + lane * HID;
  const float* wnr = Wc_n + lane * HID;
  #pragma unroll
  for (int k4 = 0; k4 < 16; ++k4){
    float4 a = *(const float4*)(wpr + 4 * k4);
    wp[4*k4] = a.x; wp[4*k4+1] = a.y; wp[4*k4+2] = a.z; wp[4*k4+3] = a.w;
    float4 b = *(const float4*)(wnr + 4 * k4);
    wn[4*k4] = b.x; wn[4*k4+1] = b.y; wn[4*k4+2] = b.z; wn[4*k4+3] = b.w;
  }
  float mp = 0.f, mn = 0.f;            // lane == feature: no cross-lane reduce needed
  int gw = blockIdx.x * 4 + wid, nw = gridDim.x * 4;
  for (int p = gw; p < N_NODES / 2; p += nw){
    int n0 = 2 * p, n1 = n0 + 1;
    float h0 = hn[n0 * HID + lane], h1 = hn[n1 * HID + lane];
    float ap0 = 0.f, an0 = 0.f, ap1 = 0.f, an1 = 0.f;
    #pragma unroll
    for (int k = 0; k < 64; ++k){
      float a = bcastf(h0, k), b = bcastf(h1, k);
      ap0 += a * wp[k]; an0 += a * wn[k];
      ap1 += b * wp[k]; an1 += b * wn[k];
    }
    ap0 *= dinv_p[n0]; an0 *= dinv_n[n0];
    ap1 *= dinv_p[n1]; an1 *= dinv_n[n1];
    tmp_p[(size_t)n0 * 64 + lane] = f2bf(ap0);
    tmp_n[(size_t)n0 * 64 + lane] = f2bf(an0);
    tmp_p[(size_t)n1 * 64 + lane] = f2bf(ap1);
    tmp_n[(size_t)n1 * 64 + lane] = f2bf(an1);
    mp = fmaxf(mp, fmaxf(fabsf(ap0), fabsf(ap1)));
    mn = fmaxf(mn, fmaxf(fabsf(an0), fabsf(an1)));
  }
  // bf16 store rounds up to 1.004x: inflate colmax so |tmp| <= colmax always
  mp *= 1.0079f; mn *= 1.0079f;
  atomicMax(&colmax[lane], __float_as_uint(mp));
  atomicMax(&colmax[64 + lane], __float_as_uint(mn));
}

// -------- convB: quantize bf16 temp -> u8 with column scales ----------------------------
__global__ __launch_bounds__(256) void convB_kernel(
    const unsigned short* __restrict__ tmp_p, const unsigned short* __restrict__ tmp_n,
    const uint* __restrict__ colmax,
    unsigned char* __restrict__ xq_p, unsigned char* __restrict__ xq_n){
  int idx8 = blockIdx.x * 256 + threadIdx.x;        // 8 elems per thread
  if (idx8 >= (N_NODES * 64) / 8) return;
  int base = idx8 * 8;
  int f0 = base & 63;
  #pragma unroll
  for (int side = 0; side < 2; ++side){
    const unsigned short* tmp = side ? tmp_n : tmp_p;
    unsigned char* xq = side ? xq_n : xq_p;
    const uint* cm = colmax + side * 64;
    uint4 v = *(const uint4*)(tmp + base);
    unsigned short e[8] = {(unsigned short)(v.x & 0xffff), (unsigned short)(v.x >> 16),
                           (unsigned short)(v.y & 0xffff), (unsigned short)(v.y >> 16),
                           (unsigned short)(v.z & 0xffff), (unsigned short)(v.z >> 16),
                           (unsigned short)(v.w & 0xffff), (unsigned short)(v.w >> 16)};
    uint out[8];
    #pragma unroll
    for (int i = 0; i < 8; ++i){
      float cmv = __uint_as_float(cm[f0 + i]);
      float inv = (cmv > 0.f) ? 127.0f / cmv : 0.f;
      int q = (int)rintf(bf2f(e[i]) * inv);
      q = q > 127 ? 127 : (q < -127 ? -127 : q);
      out[i] = (uint)(q + 128);
    }
    uint2 w2;
    w2.x = out[0] | (out[1] << 8) | (out[2] << 16) | (out[3] << 24);
    w2.y = out[4] | (out[5] << 8) | (out[6] << 16) | (out[7] << 24);
    *(uint2*)(xq + base) = w2;
  }
}

// ---------------- slow-path accumulate (deg > 64) --------------------
__device__ __forceinline__ void gather_side_acc(
    const unsigned char* __restrict__ xq, const unsigned short* __restrict__ cs,
    int s0, int s1, int g, int j8, int lane, float* acc, int& nr){
  for (int base = s0; base < s1; base += 64){
    int jj = base + lane;
    int si = (jj < s1) ? (int)cs[jj] : N_NODES;
    int cnt = min(64, s1 - base);
    int nt = (cnt + 7) >> 3;
    for (int t = 0; t < nt; ++t){
      int r = __shfl(si, 8 * t + g);
      accu8(acc, *(const uint2*)(xq + (size_t)r * 64 + j8));
      nr += 1;
    }
  }
}

// ------ gather both sides, 2 nodes/wave, u8 + column scales + RK4 + LN (fused) -----------
__global__ __launch_bounds__(256) void gatherrk_kernel(
    const unsigned char* __restrict__ xq_p, const unsigned char* __restrict__ xq_n,
    const uint* __restrict__ colmax,
    const unsigned short* __restrict__ cs_p, const int* __restrict__ off_p,
    const float* __restrict__ dinv_p,
    const unsigned short* __restrict__ cs_n, const int* __restrict__ off_n,
    const float* __restrict__ dinv_n,
    const float* __restrict__ bc, const float* __restrict__ gamma, const float* __restrict__ beta,
    const float* __restrict__ tvec,
    float* __restrict__ hbase, float* __restrict__ acc, float* __restrict__ hn,
    int st, int emit){
  int lane = threadIdx.x & 63, wid = threadIdx.x >> 6;
  int pair = blockIdx.x * 4 + wid;
  int nA = 2 * pair, nB = nA + 1;
  if (nA >= N_NODES) return;
  int g = lane >> 3, j = lane & 7, j8 = 8 * j, rowoff = j8;

  // column decode scales for this lane's 8 features
  float scolp[8], scoln[8];
  {
    float4 c0 = *(const float4*)((const float*)colmax + j8);
    float4 c1 = *(const float4*)((const float*)colmax + j8 + 4);
    float4 c2 = *(const float4*)((const float*)colmax + 64 + j8);
    float4 c3 = *(const float4*)((const float*)colmax + 64 + j8 + 4);
    const float r127 = 1.0f / 127.0f;
    scolp[0]=c0.x*r127; scolp[1]=c0.y*r127; scolp[2]=c0.z*r127; scolp[3]=c0.w*r127;
    scolp[4]=c1.x*r127; scolp[5]=c1.y*r127; scolp[6]=c1.z*r127; scolp[7]=c1.w*r127;
    scoln[0]=c2.x*r127; scoln[1]=c2.y*r127; scoln[2]=c2.z*r127; scoln[3]=c2.w*r127;
    scoln[4]=c3.x*r127; scoln[5]=c3.y*r127; scoln[6]=c3.z*r127; scoln[7]=c3.w*r127;
  }

  int pA0 = off_p[nA], pA1 = off_p[nA + 1], pB1 = off_p[nB + 1];
  int qA0 = off_n[nA], qA1 = off_n[nA + 1], qB1 = off_n[nB + 1];
  int dPA = pA1 - pA0, dPB = pB1 - pA1, dNA = qA1 - qA0, dNB = qB1 - qA1;

  float aPA[8] = {0,0,0,0,0,0,0,0};
  float aPB[8] = {0,0,0,0,0,0,0,0};
  float aNA[8] = {0,0,0,0,0,0,0,0};
  float aNB[8] = {0,0,0,0,0,0,0,0};
  int nrPA = 1, nrPB = 1, nrNA = 1, nrNB = 1;   // self rows
  {   // self rows (group 0 real, other groups hit 128-pad row -> decodes 0 with count)
    int rA = (g == 0) ? nA : N_NODES;
    int rB = (g == 0) ? nB : N_NODES;
    accu8(aPA, *(const uint2*)(xq_p + (size_t)rA * 64 + j8));
    accu8(aPB, *(const uint2*)(xq_p + (size_t)rB * 64 + j8));
    accu8(aNA, *(const uint2*)(xq_n + (size_t)rA * 64 + j8));
    accu8(aNB, *(const uint2*)(xq_n + (size_t)rB * 64 + j8));
  }

  if (dPA <= 64 && dPB <= 64 && dNA <= 64 && dNB <= 64){
    int siPA = (lane < dPA) ? (int)cs_p[pA0 + lane] : N_NODES;
    int siPB = (lane < dPB) ? (int)cs_p[pA1 + lane] : N_NODES;
    int siNA = (lane < dNA) ? (int)cs_n[qA0 + lane] : N_NODES;
    int siNB = (lane < dNB) ? (int)cs_n[qA1 + lane] : N_NODES;
    int dP = dPA > dPB ? dPA : dPB;
    int dN = dNA > dNB ? dNA : dNB;
    int ntP = (dP + 7) >> 3, ntN = (dN + 7) >> 3;
    for (int t = 0; t < ntP; t += 2){
      int gi0 = 8 * t + g, gi1 = gi0 + 8;
      int rA0 = __shfl(siPA, gi0), rB0 = __shfl(siPB, gi0);
      int rA1 = __shfl(siPA, gi1), rB1 = __shfl(siPB, gi1);
      uint2 vA0 = *(const uint2*)(xq_p + (size_t)rA0 * 64 + j8);
      uint2 vB0 = *(const uint2*)(xq_p + (size_t)rB0 * 64 + j8);
      uint2 vA1 = *(const uint2*)(xq_p + (size_t)rA1 * 64 + j8);
      uint2 vB1 = *(const uint2*)(xq_p + (size_t)rB1 * 64 + j8);
      accu8(aPA, vA0); accu8(aPB, vB0); accu8(aPA, vA1); accu8(aPB, vB1);
      nrPA += 2; nrPB += 2;
    }
    for (int t = 0; t < ntN; t += 2){
      int gi0 = 8 * t + g, gi1 = gi0 + 8;
      int rA0 = __shfl(siNA, gi0), rB0 = __shfl(siNB, gi0);
      int rA1 = __shfl(siNA, gi1), rB1 = __shfl(siNB, gi1);
      uint2 vA0 = *(const uint2*)(xq_n + (size_t)rA0 * 64 + j8);
      uint2 vB0 = *(const uint2*)(xq_n + (size_t)rB0 * 64 + j8);
      uint2 vA1 = *(const uint2*)(xq_n + (size_t)rA1 * 64 + j8);
      uint2 vB1 = *(const uint2*)(xq_n + (size_t)rB1 * 64 + j8);
      accu8(aNA, vA0); accu8(aNB, vB0); accu8(aNA, vA1); accu8(aNB, vB1);
      nrNA += 2; nrNB += 2;
    }
  } else {
    gather_side_acc(xq_p, cs_p, pA0, pA1, g, j8, lane, aPA, nrPA);
    gather_side_acc(xq_p, cs_p, pA1, pB1, g, j8, lane, aPB, nrPB);
    gather_side_acc(xq_n, cs_n, qA0, qA1, g, j8, lane, aNA, nrNA);
    gather_side_acc(xq_n, cs_n, qA1, qB1, g, j8, lane, aNB, nrNB);
  }
  // cross-group reduce; bias correction (128 per row, 8 groups) + column scale
  #pragma unroll
  for (int i = 0; i < 8; ++i){
    float a = aPA[i]; a += __shfl_xor(a, 8); a += __shfl_xor(a, 16); a += __shfl_xor(a, 32);
    aPA[i] = scolp[i] * (a - 1024.f * (float)nrPA);
    float b = aPB[i]; b += __shfl_xor(b, 8); b += __shfl_xor(b, 16); b += __shfl_xor(b, 32);
    aPB[i] = scolp[i] * (b - 1024.f * (float)nrPB);
    float c = aNA[i]; c += __shfl_xor(c, 8); c += __shfl_xor(c, 16); c += __shfl_xor(c, 32);
    aNA[i] = scoln[i] * (c - 1024.f * (float)nrNA);
    float d = aNB[i]; d += __shfl_xor(d, 8); d += __shfl_xor(d, 16); d += __shfl_xor(d, 32);
    aNB[i] = scoln[i] * (d - 1024.f * (float)nrNB);
  }

  float dvpA = dinv_p[nA], dvnA = dinv_n[nA], dvpB = dinv_p[nB], dvnB = dinv_n[nB];
  float4 b0 = *(const float4*)(bc + rowoff);
  float4 b1 = *(const float4*)(bc + rowoff + 4);
  float bcv[8] = {b0.x, b0.y, b0.z, b0.w, b1.x, b1.y, b1.z, b1.w};

  size_t ixA = (size_t)nA * HID + rowoff, ixB = (size_t)nB * HID + rowoff;
  float4 hA0 = *(const float4*)(hbase + ixA), hA1 = *(const float4*)(hbase + ixA + 4);
  float4 hB0 = *(const float4*)(hbase + ixB), hB1 = *(const float4*)(hbase + ixB + 4);
  float hbA[8] = {hA0.x,hA0.y,hA0.z,hA0.w,hA1.x,hA1.y,hA1.z,hA1.w};
  float hbB[8] = {hB0.x,hB0.y,hB0.z,hB0.w,hB1.x,hB1.y,hB1.z,hB1.w};
  float avA[8], avB[8];
  if (st != 0){
    float4 aA0 = *(const float4*)(acc + ixA), aA1 = *(const float4*)(acc + ixA + 4);
    float4 aB0 = *(const float4*)(acc + ixB), aB1 = *(const float4*)(acc + ixB + 4);
    avA[0]=aA0.x; avA[1]=aA0.y; avA[2]=aA0.z; avA[3]=aA0.w;
    avA[4]=aA1.x; avA[5]=aA1.y; avA[6]=aA1.z; avA[7]=aA1.w;
    avB[0]=aB0.x; avB[1]=aB0.y; avB[2]=aB0.z; avB[3]=aB0.w;
    avB[4]=aB1.x; avB[5]=aB1.y; avB[6]=aB1.z; avB[7]=aB1.w;
  }
  float dt = (tvec[1] - tvec[0]) * 0.5f;
  float hvA[8], hvB[8];
  #pragma unroll
  for (int i = 0; i < 8; ++i){
    float dA = dvpA * aPA[i] + dvnA * aNA[i] + bcv[i];
    float dB = dvpB * aPB[i] + dvnB * aNB[i] + bcv[i];
    dA = fminf(fmaxf(dA, -50.f), 50.f);
    dB = fminf(fmaxf(dB, -50.f), 50.f);
    if (st == 0){
      avA[i] = dA; avB[i] = dB;
      hvA[i] = hbA[i] + 0.5f * dt * dA; hvB[i] = hbB[i] + 0.5f * dt * dB;
    } else if (st == 1){
      avA[i] += 2.0f * dA; avB[i] += 2.0f * dB;
      hvA[i] = hbA[i] + 0.5f * dt * dA; hvB[i] = hbB[i] + 0.5f * dt * dB;
    } else if (st == 2){
      avA[i] += 2.0f * dA; avB[i] += 2.0f * dB;
      hvA[i] = hbA[i] + dt * dA; hvB[i] = hbB[i] + dt * dB;
    } else {
      hvA[i] = hbA[i] + (dt * (1.0f/6.0f)) * (avA[i] + dA);
      hvB[i] = hbB[i] + (dt * (1.0f/6.0f)) * (avB[i] + dB);
    }
  }
  if (st < 3){
    if (g == 0){
      float4 o0 = {avA[0],avA[1],avA[2],avA[3]}, o1 = {avA[4],avA[5],avA[6],avA[7]};
      *(float4*)(acc + ixA) = o0; *(float4*)(acc + ixA + 4) = o1;
    } else if (g == 1){
      float4 o0 = {avB[0],avB[1],avB[2],avB[3]}, o1 = {avB[4],avB[5],avB[6],avB[7]};
      *(float4*)(acc + ixB) = o0; *(float4*)(acc + ixB + 4) = o1;
    }
  } else {
    if (g == 0){
      float4 o0 = {hvA[0],hvA[1],hvA[2],hvA[3]}, o1 = {hvA[4],hvA[5],hvA[6],hvA[7]};
      *(float4*)(hbase + ixA) = o0; *(float4*)(hbase + ixA + 4) = o1;
    } else if (g == 1){
      float4 o0 = {hvB[0],hvB[1],hvB[2],hvB[3]}, o1 = {hvB[4],hvB[5],hvB[6],hvB[7]};
      *(float4*)(hbase + ixB) = o0; *(float4*)(hbase + ixB + 4) = o1;
    }
  }
  if (emit){
    float sA = 0.f, qA = 0.f, sB = 0.f, qB = 0.f;
    #pragma unroll
    for (int i = 0; i < 8; ++i){
      sA += hvA[i]; qA += hvA[i] * hvA[i];
      sB += hvB[i]; qB += hvB[i] * hvB[i];
    }
    sA += __shfl_xor(sA, 1); qA += __shfl_xor(qA, 1);
    sA += __shfl_xor(sA, 2); qA += __shfl_xor(qA, 2);
    sA += __shfl_xor(sA, 4); qA += __shfl_xor(qA, 4);
    sB += __shfl_xor(sB, 1); qB += __shfl_xor(qB, 1);
    sB += __shfl_xor(sB, 2); qB += __shfl_xor(qB, 2);
    sB += __shfl_xor(sB, 4); qB += __shfl_xor(qB, 4);
    float muA = sA * (1.0f/64.0f), varA = qA * (1.0f/64.0f) - muA * muA;
    float muB = sB * (1.0f/64.0f), varB = qB * (1.0f/64.0f) - muB * muB;
    float rsA = rsqrtf(varA + LN_EPS), rsB = rsqrtf(varB + LN_EPS);
    float4 g0 = *(const float4*)(gamma + rowoff);
    float4 g1 = *(const float4*)(gamma + rowoff + 4);
    float4 t0 = *(const float4*)(beta + rowoff);
    float4 t1 = *(const float4*)(beta + rowoff + 4);
    float gm[8] = {g0.x,g0.y,g0.z,g0.w,g1.x,g1.y,g1.z,g1.w};
    float bt[8] = {t0.x,t0.y,t0.z,t0.w,t1.x,t1.y,t1.z,t1.w};
    if (g == 0){
      float4 o0, o1;
      o0.x=(hvA[0]-muA)*rsA*gm[0]+bt[0]; o0.y=(hvA[1]-muA)*rsA*gm[1]+bt[1];
      o0.z=(hvA[2]-muA)*rsA*gm[2]+bt[2]; o0.w=(hvA[3]-muA)*rsA*gm[3]+bt[3];
      o1.x=(hvA[4]-muA)*rsA*gm[4]+bt[4]; o1.y=(hvA[5]-muA)*rsA*gm[5]+bt[5];
      o1.z=(hvA[6]-muA)*rsA*gm[6]+bt[6]; o1.w=(hvA[7]-muA)*rsA*gm[7]+bt[7];
      *(float4*)(hn + ixA) = o0; *(float4*)(hn + ixA + 4) = o1;
    } else if (g == 1){
      float4 o0, o1;
      o0.x=(hvB[0]-muB)*rsB*gm[0]+bt[0]; o0.y=(hvB[1]-muB)*rsB*gm[1]+bt[1];
      o0.z=(hvB[2]-muB)*rsB*gm[2]+bt[2]; o0.w=(hvB[3]-muB)*rsB*gm[3]+bt[3];
      o1.x=(hvB[4]-muB)*rsB*gm[4]+bt[4]; o1.y=(hvB[5]-muB)*rsB*gm[5]+bt[5];
      o1.z=(hvB[6]-muB)*rsB*gm[6]+bt[6]; o1.w=(hvB[7]-muB)*rsB*gm[7]+bt[7];
      *(float4*)(hn + ixB) = o0; *(float4*)(hn + ixB + 4) = o1;
    }
  }
}

extern "C" void kernel_launch(void* const* d_in, const int* in_sizes, int n_in,
                              void* d_out, int out_size, void* d_ws, size_t ws_size,
                              hipStream_t stream){
  const float* x     = (const float*)d_in[0];
  const int*   ep    = (const int*)d_in[1];
  const int*   en    = (const int*)d_in[2];
  const float* tvec  = (const float*)d_in[3];
  const float* W_enc = (const float*)d_in[4];
  const float* b_enc = (const float*)d_in[5];
  const float* W_pos = (const float*)d_in[6];
  const float* b_pos = (const float*)d_in[7];
  const float* W_neg = (const float*)d_in[8];
  const float* b_neg = (const float*)d_in[9];
  const float* W_pp  = (const float*)d_in[10];
  const float* b_pp  = (const float*)d_in[11];
  const float* W_pn  = (const float*)d_in[12];
  const float* b_pn  = (const float*)d_in[13];
  const float* gamma = (const float*)d_in[14];
  const float* beta  = (const float*)d_in[15];
  float* hbase = (float*)d_out;

  char* w = (char*)d_ws;
  auto alloc = [&](size_t bytes) -> char* {
    char* p = w;
    w += (bytes + 255) & ~(size_t)255;
    return p;
  };
  uint*  bin_cur = (uint*)alloc(2 * NB2 * 4);          // 3200 -> padded 3328
  uint*  colmax  = (uint*)alloc(128 * 4);              // contiguous after bin_cur
  int*   off_p = (int*)alloc((N_NODES + 1) * 4);
  int*   off_n = (int*)alloc((N_NODES + 1) * 4);
  float* dinv_p= (float*)alloc(N_NODES * 4);
  float* dinv_n= (float*)alloc(N_NODES * 4);
  uint*  recs_p= (uint*)alloc((size_t)NB2 * CAP2 * 4);
  uint*  recs_n= (uint*)alloc((size_t)NB2 * CAP2 * 4);
  unsigned short* cs_p = (unsigned short*)alloc((size_t)N_EDGES * 2);
  unsigned short* cs_n = (unsigned short*)alloc((size_t)N_EDGES * 2);
  unsigned char* xq_p = (unsigned char*)alloc((size_t)(N_NODES + 1) * 64);
  unsigned char* xq_n = (unsigned char*)alloc((size_t)(N_NODES + 1) * 64);
  unsigned short* tmp_p = (unsigned short*)alloc((size_t)N_NODES * 64 * 2);
  unsigned short* tmp_n = (unsigned short*)alloc((size_t)N_NODES * 64 * 2);
  float* hn    = (float*)alloc((size_t)N_NODES * HID * 4);
  float* accb  = (float*)alloc((size_t)N_NODES * HID * 4);
  float* Wc_p  = (float*)alloc(HID * HID * 4);
  float* Wc_n  = (float*)alloc(HID * HID * 4);
  float* bc    = (float*)alloc(HID * 4);

  // zero bin_cur + colmax in one shot (contiguous allocs; colmax monotone across stages)
  hipMemsetAsync(bin_cur, 0, 3328 + 512, stream);

  dim3 blk(256);
  const int NBLK_A = 2 * ((N_EDGES + 8191) / 8192);
  prep_kernel<<<17, blk, 0, stream>>>(W_pp, W_pos, W_pn, W_neg, b_pos, b_pp, b_neg, b_pn,
                                      Wc_p, Wc_n, bc, xq_p, xq_n);
  binA_kernel<<<NBLK_A, blk, 0, stream>>>(ep, en, bin_cur, recs_p, recs_n);
  fillC_kernel<<<2 * NB2, blk, 0, stream>>>(bin_cur, recs_p, recs_n,
                                            off_p, off_n, dinv_p, dinv_n, cs_p, cs_n);
  enc_kernel<<<1024, blk, 0, stream>>>(x, W_enc, b_enc, gamma, beta, hbase, hn);

  const int NBLK_QB = (N_NODES * 64 / 8 + 255) / 256;
  for (int s = 0; s < 8; ++s){
    convA_kernel<<<1024, blk, 0, stream>>>(hn, Wc_p, Wc_n, dinv_p, dinv_n,
                                           tmp_p, tmp_n, colmax);
    convB_kernel<<<NBLK_QB, blk, 0, stream>>>(tmp_p, tmp_n, colmax, xq_p, xq_n);
    gatherrk_kernel<<<(N_NODES / 2 + 3) / 4, blk, 0, stream>>>(
        xq_p, xq_n, colmax, cs_p, off_p, dinv_p, cs_n, off_n, dinv_n,
        bc, gamma, beta, tvec, hbase, accb, hn, s & 3, (s < 7) ? 1 : 0);
  }
}

// Round 9
// 1337.443 us; speedup vs baseline: 1.2192x; 1.2192x over previous
//
#include <hip/hip_runtime.h>

#define N_NODES 50000
#define N_FEAT  128
#define HID     64
#define N_EDGES 1600000
#define LN_EPS  1e-5f
#define NB2     400          // bins per side
#define BW2     125          // nodes per bin (400*125 = 50000)
#define CAP2    5120u        // per-bin record capacity (mean 4000, +17 sigma)

typedef unsigned int uint;

__device__ __forceinline__ float bcastf(float v, int l){
  return __uint_as_float(__builtin_amdgcn_readlane(__float_as_uint(v), l));
}
__device__ __forceinline__ unsigned short f2bf(float f){
  unsigned u = __float_as_uint(f);
  unsigned r = (u + 0x7fff + ((u >> 16) & 1)) >> 16;
  return (unsigned short)r;
}
__device__ __forceinline__ float bf2f(unsigned short u){
  return __uint_as_float(((unsigned)u) << 16);
}
// unscaled u8 accumulate (2 VALU/elem: cvt + add); bias 128 corrected once per node
__device__ __forceinline__ void accu8(float* a, uint2 v){
  a[0] += (float)( v.x         & 0xffu);
  a[1] += (float)((v.x >> 8)   & 0xffu);
  a[2] += (float)((v.x >> 16)  & 0xffu);
  a[3] += (float)( v.x >> 24         );
  a[4] += (float)( v.y         & 0xffu);
  a[5] += (float)((v.y >> 8)   & 0xffu);
  a[6] += (float)((v.y >> 16)  & 0xffu);
  a[7] += (float)( v.y >> 24         );
}

// ---------------- precompute: Wc = Wpsi @ W, bc = combined bias, pad rows = 128 ---------
__global__ void prep_kernel(const float* __restrict__ Wpp, const float* __restrict__ Wp,
                            const float* __restrict__ Wpn, const float* __restrict__ Wn,
                            const float* __restrict__ bp, const float* __restrict__ bpp,
                            const float* __restrict__ bn, const float* __restrict__ bpn,
                            float* __restrict__ Wc_p, float* __restrict__ Wc_n,
                            float* __restrict__ bc,
                            unsigned char* __restrict__ xq_p, unsigned char* __restrict__ xq_n){
  int idx = blockIdx.x * blockDim.x + threadIdx.x;
  if (idx < 4096){
    int j = idx >> 6, k = idx & 63;
    float sp = 0.f, sn = 0.f;
    for (int m = 0; m < 64; ++m){
      sp += Wpp[j * 64 + m] * Wp[m * 64 + k];
      sn += Wpn[j * 64 + m] * Wn[m * 64 + k];
    }
    Wc_p[idx] = sp; Wc_n[idx] = sn;
  } else if (idx < 4160){
    int j = idx - 4096;
    float s = bpp[j] + bpn[j];
    for (int m = 0; m < 64; ++m) s += Wpp[j * 64 + m] * bp[m] + Wpn[j * 64 + m] * bn[m];
    bc[j] = s;
  } else if (idx < 4224){
    // pad row decodes to exactly 0: byte 128 with bias-128 correction
    xq_p[(size_t)N_NODES * 64 + (idx - 4160)] = 128;
    xq_n[(size_t)N_NODES * 64 + (idx - 4160)] = 128;
  }
}

// ---------------- phase A: bin edges by dst range (400 bins/side) ----------------
__global__ __launch_bounds__(256) void binA_kernel(
    const int* __restrict__ ep, const int* __restrict__ en,
    uint* __restrict__ bin_cur, uint* __restrict__ recs_p, uint* __restrict__ recs_n){
  __shared__ uint sh[8192];
  __shared__ uint cnt2[NB2], gb2[NB2], rnk2[NB2];
  const int NBLK = (N_EDGES + 8191) / 8192;
  int bid = blockIdx.x;
  int side = bid >= NBLK;
  const int* e = side ? en : ep;
  uint* recs = side ? recs_n : recs_p;
  uint* bcur = bin_cur + side * NB2;
  int cbase = (side ? bid - NBLK : bid) * 8192;
  int tid = threadIdx.x;
  for (int i = tid; i < NB2; i += 256){ cnt2[i] = 0; rnk2[i] = 0; }
  __syncthreads();
  for (int i = tid; i < 8192; i += 256){
    int t = cbase + i;
    uint r = 0xFFFFFFFFu;
    if (t < N_EDGES){
      uint s = (uint)e[t], d = (uint)e[N_EDGES + t];
      r = (d << 16) | s;
      atomicAdd(&cnt2[d / BW2], 1u);
    }
    sh[i] = r;
  }
  __syncthreads();
  for (int i = tid; i < NB2; i += 256) gb2[i] = atomicAdd(&bcur[i], cnt2[i]);
  __syncthreads();
  for (int i = tid; i < 8192; i += 256){
    uint r = sh[i];
    if (r != 0xFFFFFFFFu){
      uint b = (r >> 16) / BW2;
      uint pos = gb2[b] + atomicAdd(&rnk2[b], 1u);
      recs[b * CAP2 + pos] = r;
    }
  }
}

// -------- LDS counting sort per bin: dinv, off (global CSR offsets), cs (coalesced) ------
__global__ __launch_bounds__(256) void fillC_kernel(
    const uint* __restrict__ bin_cur,
    const uint* __restrict__ recs_p, const uint* __restrict__ recs_n,
    int* __restrict__ off_p, int* __restrict__ off_n,
    float* __restrict__ dinv_p, float* __restrict__ dinv_n,
    unsigned short* __restrict__ cs_p, unsigned short* __restrict__ cs_n){
  __shared__ int hist[128];
  __shared__ int curx[128];
  __shared__ unsigned short staged[CAP2];
  __shared__ uint base_s;
  int bid = blockIdx.x;
  int side = bid >= NB2; int b = side ? bid - NB2 : bid;
  const uint* recs = (side ? recs_n : recs_p) + (size_t)b * CAP2;
  int* off = side ? off_n : off_p;
  float* dinv = side ? dinv_n : dinv_p;
  unsigned short* cs = side ? cs_n : cs_p;
  int tid = threadIdx.x, lane = tid & 63, wid = tid >> 6;
  int nodebase = b * BW2;
  if (tid < 128) hist[tid] = 0;
  __syncthreads();
  uint n = bin_cur[side * NB2 + b];
  if (wid == 1){                        // bin's global output base
    uint s = 0;
    for (int k = lane; k < b; k += 64) s += bin_cur[side * NB2 + k];
    #pragma unroll
    for (int d = 1; d < 64; d <<= 1) s += __shfl_xor(s, d);
    if (lane == 0) base_s = s;
  }
  for (uint i = tid; i < n; i += 256)
    atomicAdd(&hist[(recs[i] >> 16) - nodebase], 1);
  __syncthreads();
  if (tid < BW2)
    dinv[nodebase + tid] = rsqrtf((float)(hist[tid] + 1));
  if (wid == 0){                        // exclusive scan hist -> curx
    int carry = 0;
    #pragma unroll
    for (int base = 0; base < BW2; base += 64){
      int idx = base + lane;
      int v = (idx < BW2) ? hist[idx] : 0;
      int x = v;
      #pragma unroll
      for (int d = 1; d < 64; d <<= 1){
        int y = __shfl_up(x, d);
        if (lane >= d) x += y;
      }
      if (idx < BW2) curx[idx] = carry + x - v;
      int tot = __shfl(x, 63);
      carry = carry + tot;
    }
  }
  __syncthreads();
  if (tid < BW2) off[nodebase + tid] = (int)base_s + curx[tid];
  if (b == NB2 - 1 && tid == 0) off[N_NODES] = (int)(base_s + n);
  __syncthreads();
  for (uint i = tid; i < n; i += 256){
    uint r = recs[i];
    int d = (int)(r >> 16) - nodebase;
    int p = atomicAdd(&curx[d], 1);
    staged[p] = (unsigned short)(r & 0xFFFFu);
  }
  __syncthreads();
  uint base = base_s;
  for (uint i = tid; i < n; i += 256) cs[base + i] = staged[i];
}

// ---- enc pass 1: part = x[:, 0:64] @ Wenc[:, 0:64]^T  (64 weight VGPRs per lane) -------
// R7/R8 lesson: a 128-float per-lane array gets left in scratch by the allocator
// (VGPR_Count=84, dur 99us, VALUBusy 17%). Keep per-lane weight arrays <= 64 floats.
__global__ __launch_bounds__(256) void enc1_kernel(
    const float* __restrict__ x, const float* __restrict__ Wenc,
    float* __restrict__ part){
  int lane = threadIdx.x & 63, wid = threadIdx.x >> 6;
  float we[64];
  const float* wr = Wenc + lane * N_FEAT;
  #pragma unroll
  for (int k4 = 0; k4 < 16; ++k4){
    float4 v = *(const float4*)(wr + 4 * k4);
    we[4*k4] = v.x; we[4*k4+1] = v.y; we[4*k4+2] = v.z; we[4*k4+3] = v.w;
  }
  int gw = blockIdx.x * 4 + wid, nw = gridDim.x * 4;
  for (int p = gw; p < N_NODES / 2; p += nw){
    int n0 = 2 * p, n1 = n0 + 1;
    float xa0 = x[(size_t)n0 * N_FEAT + lane];
    float xa1 = x[(size_t)n1 * N_FEAT + lane];
    float h0 = 0.f, h1 = 0.f;
    #pragma unroll
    for (int k = 0; k < 64; ++k){
      h0 += bcastf(xa0, k) * we[k];
      h1 += bcastf(xa1, k) * we[k];
    }
    part[n0 * HID + lane] = h0;
    part[n1 * HID + lane] = h1;
  }
}

// ---- enc pass 2: h = part + x[:, 64:128] @ Wenc[:, 64:128]^T + b; LN -> hbase, hn ------
__global__ __launch_bounds__(256) void enc2_kernel(
    const float* __restrict__ x, const float* __restrict__ Wenc, const float* __restrict__ benc,
    const float* __restrict__ gamma, const float* __restrict__ beta,
    const float* __restrict__ part,
    float* __restrict__ hbase, float* __restrict__ hn){
  int lane = threadIdx.x & 63, wid = threadIdx.x >> 6;
  float we[64];
  const float* wr = Wenc + lane * N_FEAT + 64;
  #pragma unroll
  for (int k4 = 0; k4 < 16; ++k4){
    float4 v = *(const float4*)(wr + 4 * k4);
    we[4*k4] = v.x; we[4*k4+1] = v.y; we[4*k4+2] = v.z; we[4*k4+3] = v.w;
  }
  float bv = benc[lane], g = gamma[lane], bt = beta[lane];
  int gw = blockIdx.x * 4 + wid, nw = gridDim.x * 4;
  for (int p = gw; p < N_NODES / 2; p += nw){
    int n0 = 2 * p, n1 = n0 + 1;
    float xb0 = x[(size_t)n0 * N_FEAT + 64 + lane];
    float xb1 = x[(size_t)n1 * N_FEAT + 64 + lane];
    float h0 = bv + part[n0 * HID + lane];
    float h1 = bv + part[n1 * HID + lane];
    #pragma unroll
    for (int k = 0; k < 64; ++k){
      h0 += bcastf(xb0, k) * we[k];
      h1 += bcastf(xb1, k) * we[k];
    }
    hbase[n0 * HID + lane] = h0;
    hbase[n1 * HID + lane] = h1;
    float s0 = h0, q0 = h0 * h0, s1 = h1, q1 = h1 * h1;
    #pragma unroll
    for (int d = 1; d < 64; d <<= 1){
      s0 += __shfl_xor(s0, d); q0 += __shfl_xor(q0, d);
      s1 += __shfl_xor(s1, d); q1 += __shfl_xor(q1, d);
    }
    float mu0 = s0 * (1.0f/64.0f), var0 = q0 * (1.0f/64.0f) - mu0 * mu0;
    float mu1 = s1 * (1.0f/64.0f), var1 = q1 * (1.0f/64.0f) - mu1 * mu1;
    hn[n0 * HID + lane] = (h0 - mu0) * rsqrtf(var0 + LN_EPS) * g + bt;
    hn[n1 * HID + lane] = (h1 - mu1) * rsqrtf(var1 + LN_EPS) * g + bt;
  }
}

// -------- convA: side-split GEMV. Each wave handles ONE side -> only 64 weight VGPRs ----
// R7/R8: the 128-float (both-sides) version spilled (VGPR=84, 99us). Side split keeps
// the per-lane array at 64 floats; work spreads over 2x waves, same total FLOPs.
__global__ __launch_bounds__(256) void convA_kernel(
    const float* __restrict__ hn, const float* __restrict__ Wc_p, const float* __restrict__ Wc_n,
    const float* __restrict__ dinv_p, const float* __restrict__ dinv_n,
    unsigned short* __restrict__ tmp_p, unsigned short* __restrict__ tmp_n,
    uint* __restrict__ colmax){
  int lane = threadIdx.x & 63, wid = threadIdx.x >> 6;
  int side = wid & 1;                 // waves 0,2: pos; waves 1,3: neg
  const float* Wc   = side ? Wc_n   : Wc_p;
  const float* dinv = side ? dinv_n : dinv_p;
  unsigned short* tmp = side ? tmp_n : tmp_p;
  float w[64];
  const float* wr = Wc + lane * HID;
  #pragma unroll
  for (int k4 = 0; k4 < 16; ++k4){
    float4 a = *(const float4*)(wr + 4 * k4);
    w[4*k4] = a.x; w[4*k4+1] = a.y; w[4*k4+2] = a.z; w[4*k4+3] = a.w;
  }
  float m = 0.f;                      // lane == feature: colmax needs no cross-lane reduce
  int gw = blockIdx.x * 2 + (wid >> 1), nw = gridDim.x * 2;
  for (int p = gw; p < N_NODES / 2; p += nw){
    int n0 = 2 * p, n1 = n0 + 1;
    float h0 = hn[n0 * HID + lane], h1 = hn[n1 * HID + lane];
    float a0 = 0.f, a1 = 0.f;
    #pragma unroll
    for (int k = 0; k < 64; ++k){
      a0 += bcastf(h0, k) * w[k];
      a1 += bcastf(h1, k) * w[k];
    }
    a0 *= dinv[n0]; a1 *= dinv[n1];
    tmp[(size_t)n0 * 64 + lane] = f2bf(a0);
    tmp[(size_t)n1 * 64 + lane] = f2bf(a1);
    m = fmaxf(m, fmaxf(fabsf(a0), fabsf(a1)));
  }
  // bf16 store rounds up to 1.004x: inflate colmax so |tmp| <= colmax always
  m *= 1.0079f;
  atomicMax(&colmax[side * 64 + lane], __float_as_uint(m));
}

// -------- convB: quantize bf16 temp -> u8 with column scales ----------------------------
__global__ __launch_bounds__(256) void convB_kernel(
    const unsigned short* __restrict__ tmp_p, const unsigned short* __restrict__ tmp_n,
    const uint* __restrict__ colmax,
    unsigned char* __restrict__ xq_p, unsigned char* __restrict__ xq_n){
  int idx8 = blockIdx.x * 256 + threadIdx.x;        // 8 elems per thread
  if (idx8 >= (N_NODES * 64) / 8) return;
  int base = idx8 * 8;
  int f0 = base & 63;
  #pragma unroll
  for (int side = 0; side < 2; ++side){
    const unsigned short* tmp = side ? tmp_n : tmp_p;
    unsigned char* xq = side ? xq_n : xq_p;
    const uint* cm = colmax + side * 64;
    uint4 v = *(const uint4*)(tmp + base);
    unsigned short e[8] = {(unsigned short)(v.x & 0xffff), (unsigned short)(v.x >> 16),
                           (unsigned short)(v.y & 0xffff), (unsigned short)(v.y >> 16),
                           (unsigned short)(v.z & 0xffff), (unsigned short)(v.z >> 16),
                           (unsigned short)(v.w & 0xffff), (unsigned short)(v.w >> 16)};
    uint out[8];
    #pragma unroll
    for (int i = 0; i < 8; ++i){
      float cmv = __uint_as_float(cm[f0 + i]);
      float inv = (cmv > 0.f) ? 127.0f / cmv : 0.f;
      int q = (int)rintf(bf2f(e[i]) * inv);
      q = q > 127 ? 127 : (q < -127 ? -127 : q);
      out[i] = (uint)(q + 128);
    }
    uint2 w2;
    w2.x = out[0] | (out[1] << 8) | (out[2] << 16) | (out[3] << 24);
    w2.y = out[4] | (out[5] << 8) | (out[6] << 16) | (out[7] << 24);
    *(uint2*)(xq + base) = w2;
  }
}

// ---------------- slow-path accumulate (deg > 64) --------------------
__device__ __forceinline__ void gather_side_acc(
    const unsigned char* __restrict__ xq, const unsigned short* __restrict__ cs,
    int s0, int s1, int g, int j8, int lane, float* acc, int& nr){
  for (int base = s0; base < s1; base += 64){
    int jj = base + lane;
    int si = (jj < s1) ? (int)cs[jj] : N_NODES;
    int cnt = min(64, s1 - base);
    int nt = (cnt + 7) >> 3;
    for (int t = 0; t < nt; ++t){
      int r = __shfl(si, 8 * t + g);
      accu8(acc, *(const uint2*)(xq + (size_t)r * 64 + j8));
      nr += 1;
    }
  }
}

// ------ gather both sides, 2 nodes/wave, u8 + column scales + RK4 + LN (fused) -----------
__global__ __launch_bounds__(256) void gatherrk_kernel(
    const unsigned char* __restrict__ xq_p, const unsigned char* __restrict__ xq_n,
    const uint* __restrict__ colmax,
    const unsigned short* __restrict__ cs_p, const int* __restrict__ off_p,
    const float* __restrict__ dinv_p,
    const unsigned short* __restrict__ cs_n, const int* __restrict__ off_n,
    const float* __restrict__ dinv_n,
    const float* __restrict__ bc, const float* __restrict__ gamma, const float* __restrict__ beta,
    const float* __restrict__ tvec,
    float* __restrict__ hbase, float* __restrict__ acc, float* __restrict__ hn,
    int st, int emit){
  int lane = threadIdx.x & 63, wid = threadIdx.x >> 6;
  int pair = blockIdx.x * 4 + wid;
  int nA = 2 * pair, nB = nA + 1;
  if (nA >= N_NODES) return;
  int g = lane >> 3, j = lane & 7, j8 = 8 * j, rowoff = j8;

  // column decode scales for this lane's 8 features
  float scolp[8], scoln[8];
  {
    float4 c0 = *(const float4*)((const float*)colmax + j8);
    float4 c1 = *(const float4*)((const float*)colmax + j8 + 4);
    float4 c2 = *(const float4*)((const float*)colmax + 64 + j8);
    float4 c3 = *(const float4*)((const float*)colmax + 64 + j8 + 4);
    const float r127 = 1.0f / 127.0f;
    scolp[0]=c0.x*r127; scolp[1]=c0.y*r127; scolp[2]=c0.z*r127; scolp[3]=c0.w*r127;
    scolp[4]=c1.x*r127; scolp[5]=c1.y*r127; scolp[6]=c1.z*r127; scolp[7]=c1.w*r127;
    scoln[0]=c2.x*r127; scoln[1]=c2.y*r127; scoln[2]=c2.z*r127; scoln[3]=c2.w*r127;
    scoln[4]=c3.x*r127; scoln[5]=c3.y*r127; scoln[6]=c3.z*r127; scoln[7]=c3.w*r127;
  }

  int pA0 = off_p[nA], pA1 = off_p[nA + 1], pB1 = off_p[nB + 1];
  int qA0 = off_n[nA], qA1 = off_n[nA + 1], qB1 = off_n[nB + 1];
  int dPA = pA1 - pA0, dPB = pB1 - pA1, dNA = qA1 - qA0, dNB = qB1 - qA1;

  float aPA[8] = {0,0,0,0,0,0,0,0};
  float aPB[8] = {0,0,0,0,0,0,0,0};
  float aNA[8] = {0,0,0,0,0,0,0,0};
  float aNB[8] = {0,0,0,0,0,0,0,0};
  int nrPA = 1, nrPB = 1, nrNA = 1, nrNB = 1;   // self rows
  {   // self rows (group 0 real, other groups hit 128-pad row -> decodes 0 with count)
    int rA = (g == 0) ? nA : N_NODES;
    int rB = (g == 0) ? nB : N_NODES;
    accu8(aPA, *(const uint2*)(xq_p + (size_t)rA * 64 + j8));
    accu8(aPB, *(const uint2*)(xq_p + (size_t)rB * 64 + j8));
    accu8(aNA, *(const uint2*)(xq_n + (size_t)rA * 64 + j8));
    accu8(aNB, *(const uint2*)(xq_n + (size_t)rB * 64 + j8));
  }

  if (dPA <= 64 && dPB <= 64 && dNA <= 64 && dNB <= 64){
    int siPA = (lane < dPA) ? (int)cs_p[pA0 + lane] : N_NODES;
    int siPB = (lane < dPB) ? (int)cs_p[pA1 + lane] : N_NODES;
    int siNA = (lane < dNA) ? (int)cs_n[qA0 + lane] : N_NODES;
    int siNB = (lane < dNB) ? (int)cs_n[qA1 + lane] : N_NODES;
    int dP = dPA > dPB ? dPA : dPB;
    int dN = dNA > dNB ? dNA : dNB;
    int ntP = (dP + 7) >> 3, ntN = (dN + 7) >> 3;
    for (int t = 0; t < ntP; t += 2){
      int gi0 = 8 * t + g, gi1 = gi0 + 8;
      int rA0 = __shfl(siPA, gi0), rB0 = __shfl(siPB, gi0);
      int rA1 = __shfl(siPA, gi1), rB1 = __shfl(siPB, gi1);
      uint2 vA0 = *(const uint2*)(xq_p + (size_t)rA0 * 64 + j8);
      uint2 vB0 = *(const uint2*)(xq_p + (size_t)rB0 * 64 + j8);
      uint2 vA1 = *(const uint2*)(xq_p + (size_t)rA1 * 64 + j8);
      uint2 vB1 = *(const uint2*)(xq_p + (size_t)rB1 * 64 + j8);
      accu8(aPA, vA0); accu8(aPB, vB0); accu8(aPA, vA1); accu8(aPB, vB1);
      nrPA += 2; nrPB += 2;
    }
    for (int t = 0; t < ntN; t += 2){
      int gi0 = 8 * t + g, gi1 = gi0 + 8;
      int rA0 = __shfl(siNA, gi0), rB0 = __shfl(siNB, gi0);
      int rA1 = __shfl(siNA, gi1), rB1 = __shfl(siNB, gi1);
      uint2 vA0 = *(const uint2*)(xq_n + (size_t)rA0 * 64 + j8);
      uint2 vB0 = *(const uint2*)(xq_n + (size_t)rB0 * 64 + j8);
      uint2 vA1 = *(const uint2*)(xq_n + (size_t)rA1 * 64 + j8);
      uint2 vB1 = *(const uint2*)(xq_n + (size_t)rB1 * 64 + j8);
      accu8(aNA, vA0); accu8(aNB, vB0); accu8(aNA, vA1); accu8(aNB, vB1);
      nrNA += 2; nrNB += 2;
    }
  } else {
    gather_side_acc(xq_p, cs_p, pA0, pA1, g, j8, lane, aPA, nrPA);
    gather_side_acc(xq_p, cs_p, pA1, pB1, g, j8, lane, aPB, nrPB);
    gather_side_acc(xq_n, cs_n, qA0, qA1, g, j8, lane, aNA, nrNA);
    gather_side_acc(xq_n, cs_n, qA1, qB1, g, j8, lane, aNB, nrNB);
  }
  // cross-group reduce; bias correction (128 per row, 8 groups) + column scale
  #pragma unroll
  for (int i = 0; i < 8; ++i){
    float a = aPA[i]; a += __shfl_xor(a, 8); a += __shfl_xor(a, 16); a += __shfl_xor(a, 32);
    aPA[i] = scolp[i] * (a - 1024.f * (float)nrPA);
    float b = aPB[i]; b += __shfl_xor(b, 8); b += __shfl_xor(b, 16); b += __shfl_xor(b, 32);
    aPB[i] = scolp[i] * (b - 1024.f * (float)nrPB);
    float c = aNA[i]; c += __shfl_xor(c, 8); c += __shfl_xor(c, 16); c += __shfl_xor(c, 32);
    aNA[i] = scoln[i] * (c - 1024.f * (float)nrNA);
    float d = aNB[i]; d += __shfl_xor(d, 8); d += __shfl_xor(d, 16); d += __shfl_xor(d, 32);
    aNB[i] = scoln[i] * (d - 1024.f * (float)nrNB);
  }

  float dvpA = dinv_p[nA], dvnA = dinv_n[nA], dvpB = dinv_p[nB], dvnB = dinv_n[nB];
  float4 b0 = *(const float4*)(bc + rowoff);
  float4 b1 = *(const float4*)(bc + rowoff + 4);
  float bcv[8] = {b0.x, b0.y, b0.z, b0.w, b1.x, b1.y, b1.z, b1.w};

  size_t ixA = (size_t)nA * HID + rowoff, ixB = (size_t)nB * HID + rowoff;
  float4 hA0 = *(const float4*)(hbase + ixA), hA1 = *(const float4*)(hbase + ixA + 4);
  float4 hB0 = *(const float4*)(hbase + ixB), hB1 = *(const float4*)(hbase + ixB + 4);
  float hbA[8] = {hA0.x,hA0.y,hA0.z,hA0.w,hA1.x,hA1.y,hA1.z,hA1.w};
  float hbB[8] = {hB0.x,hB0.y,hB0.z,hB0.w,hB1.x,hB1.y,hB1.z,hB1.w};
  float avA[8], avB[8];
  if (st != 0){
    float4 aA0 = *(const float4*)(acc + ixA), aA1 = *(const float4*)(acc + ixA + 4);
    float4 aB0 = *(const float4*)(acc + ixB), aB1 = *(const float4*)(acc + ixB + 4);
    avA[0]=aA0.x; avA[1]=aA0.y; avA[2]=aA0.z; avA[3]=aA0.w;
    avA[4]=aA1.x; avA[5]=aA1.y; avA[6]=aA1.z; avA[7]=aA1.w;
    avB[0]=aB0.x; avB[1]=aB0.y; avB[2]=aB0.z; avB[3]=aB0.w;
    avB[4]=aB1.x; avB[5]=aB1.y; avB[6]=aB1.z; avB[7]=aB1.w;
  }
  float dt = (tvec[1] - tvec[0]) * 0.5f;
  float hvA[8], hvB[8];
  #pragma unroll
  for (int i = 0; i < 8; ++i){
    float dA = dvpA * aPA[i] + dvnA * aNA[i] + bcv[i];
    float dB = dvpB * aPB[i] + dvnB * aNB[i] + bcv[i];
    dA = fminf(fmaxf(dA, -50.f), 50.f);
    dB = fminf(fmaxf(dB, -50.f), 50.f);
    if (st == 0){
      avA[i] = dA; avB[i] = dB;
      hvA[i] = hbA[i] + 0.5f * dt * dA; hvB[i] = hbB[i] + 0.5f * dt * dB;
    } else if (st == 1){
      avA[i] += 2.0f * dA; avB[i] += 2.0f * dB;
      hvA[i] = hbA[i] + 0.5f * dt * dA; hvB[i] = hbB[i] + 0.5f * dt * dB;
    } else if (st == 2){
      avA[i] += 2.0f * dA; avB[i] += 2.0f * dB;
      hvA[i] = hbA[i] + dt * dA; hvB[i] = hbB[i] + dt * dB;
    } else {
      hvA[i] = hbA[i] + (dt * (1.0f/6.0f)) * (avA[i] + dA);
      hvB[i] = hbB[i] + (dt * (1.0f/6.0f)) * (avB[i] + dB);
    }
  }
  if (st < 3){
    if (g == 0){
      float4 o0 = {avA[0],avA[1],avA[2],avA[3]}, o1 = {avA[4],avA[5],avA[6],avA[7]};
      *(float4*)(acc + ixA) = o0; *(float4*)(acc + ixA + 4) = o1;
    } else if (g == 1){
      float4 o0 = {avB[0],avB[1],avB[2],avB[3]}, o1 = {avB[4],avB[5],avB[6],avB[7]};
      *(float4*)(acc + ixB) = o0; *(float4*)(acc + ixB + 4) = o1;
    }
  } else {
    if (g == 0){
      float4 o0 = {hvA[0],hvA[1],hvA[2],hvA[3]}, o1 = {hvA[4],hvA[5],hvA[6],hvA[7]};
      *(float4*)(hbase + ixA) = o0; *(float4*)(hbase + ixA + 4) = o1;
    } else if (g == 1){
      float4 o0 = {hvB[0],hvB[1],hvB[2],hvB[3]}, o1 = {hvB[4],hvB[5],hvB[6],hvB[7]};
      *(float4*)(hbase + ixB) = o0; *(float4*)(hbase + ixB + 4) = o1;
    }
  }
  if (emit){
    float sA = 0.f, qA = 0.f, sB = 0.f, qB = 0.f;
    #pragma unroll
    for (int i = 0; i < 8; ++i){
      sA += hvA[i]; qA += hvA[i] * hvA[i];
      sB += hvB[i]; qB += hvB[i] * hvB[i];
    }
    sA += __shfl_xor(sA, 1); qA += __shfl_xor(qA, 1);
    sA += __shfl_xor(sA, 2); qA += __shfl_xor(qA, 2);
    sA += __shfl_xor(sA, 4); qA += __shfl_xor(qA, 4);
    sB += __shfl_xor(sB, 1); qB += __shfl_xor(qB, 1);
    sB += __shfl_xor(sB, 2); qB += __shfl_xor(qB, 2);
    sB += __shfl_xor(sB, 4); qB += __shfl_xor(qB, 4);
    float muA = sA * (1.0f/64.0f), varA = qA * (1.0f/64.0f) - muA * muA;
    float muB = sB * (1.0f/64.0f), varB = qB * (1.0f/64.0f) - muB * muB;
    float rsA = rsqrtf(varA + LN_EPS), rsB = rsqrtf(varB + LN_EPS);
    float4 g0 = *(const float4*)(gamma + rowoff);
    float4 g1 = *(const float4*)(gamma + rowoff + 4);
    float4 t0 = *(const float4*)(beta + rowoff);
    float4 t1 = *(const float4*)(beta + rowoff + 4);
    float gm[8] = {g0.x,g0.y,g0.z,g0.w,g1.x,g1.y,g1.z,g1.w};
    float bt[8] = {t0.x,t0.y,t0.z,t0.w,t1.x,t1.y,t1.z,t1.w};
    if (g == 0){
      float4 o0, o1;
      o0.x=(hvA[0]-muA)*rsA*gm[0]+bt[0]; o0.y=(hvA[1]-muA)*rsA*gm[1]+bt[1];
      o0.z=(hvA[2]-muA)*rsA*gm[2]+bt[2]; o0.w=(hvA[3]-muA)*rsA*gm[3]+bt[3];
      o1.x=(hvA[4]-muA)*rsA*gm[4]+bt[4]; o1.y=(hvA[5]-muA)*rsA*gm[5]+bt[5];
      o1.z=(hvA[6]-muA)*rsA*gm[6]+bt[6]; o1.w=(hvA[7]-muA)*rsA*gm[7]+bt[7];
      *(float4*)(hn + ixA) = o0; *(float4*)(hn + ixA + 4) = o1;
    } else if (g == 1){
      float4 o0, o1;
      o0.x=(hvB[0]-muB)*rsB*gm[0]+bt[0]; o0.y=(hvB[1]-muB)*rsB*gm[1]+bt[1];
      o0.z=(hvB[2]-muB)*rsB*gm[2]+bt[2]; o0.w=(hvB[3]-muB)*rsB*gm[3]+bt[3];
      o1.x=(hvB[4]-muB)*rsB*gm[4]+bt[4]; o1.y=(hvB[5]-muB)*rsB*gm[5]+bt[5];
      o1.z=(hvB[6]-muB)*rsB*gm[6]+bt[6]; o1.w=(hvB[7]-muB)*rsB*gm[7]+bt[7];
      *(float4*)(hn + ixB) = o0; *(float4*)(hn + ixB + 4) = o1;
    }
  }
}

extern "C" void kernel_launch(void* const* d_in, const int* in_sizes, int n_in,
                              void* d_out, int out_size, void* d_ws, size_t ws_size,
                              hipStream_t stream){
  const float* x     = (const float*)d_in[0];
  const int*   ep    = (const int*)d_in[1];
  const int*   en    = (const int*)d_in[2];
  const float* tvec  = (const float*)d_in[3];
  const float* W_enc = (const float*)d_in[4];
  const float* b_enc = (const float*)d_in[5];
  const float* W_pos = (const float*)d_in[6];
  const float* b_pos = (const float*)d_in[7];
  const float* W_neg = (const float*)d_in[8];
  const float* b_neg = (const float*)d_in[9];
  const float* W_pp  = (const float*)d_in[10];
  const float* b_pp  = (const float*)d_in[11];
  const float* W_pn  = (const float*)d_in[12];
  const float* b_pn  = (const float*)d_in[13];
  const float* gamma = (const float*)d_in[14];
  const float* beta  = (const float*)d_in[15];
  float* hbase = (float*)d_out;

  char* w = (char*)d_ws;
  auto alloc = [&](size_t bytes) -> char* {
    char* p = w;
    w += (bytes + 255) & ~(size_t)255;
    return p;
  };
  uint*  bin_cur = (uint*)alloc(2 * NB2 * 4);          // 3200 -> padded 3328
  uint*  colmax  = (uint*)alloc(128 * 4);              // contiguous after bin_cur
  int*   off_p = (int*)alloc((N_NODES + 1) * 4);
  int*   off_n = (int*)alloc((N_NODES + 1) * 4);
  float* dinv_p= (float*)alloc(N_NODES * 4);
  float* dinv_n= (float*)alloc(N_NODES * 4);
  uint*  recs_p= (uint*)alloc((size_t)NB2 * CAP2 * 4);
  uint*  recs_n= (uint*)alloc((size_t)NB2 * CAP2 * 4);
  unsigned short* cs_p = (unsigned short*)alloc((size_t)N_EDGES * 2);
  unsigned short* cs_n = (unsigned short*)alloc((size_t)N_EDGES * 2);
  unsigned char* xq_p = (unsigned char*)alloc((size_t)(N_NODES + 1) * 64);
  unsigned char* xq_n = (unsigned char*)alloc((size_t)(N_NODES + 1) * 64);
  unsigned short* tmp_p = (unsigned short*)alloc((size_t)N_NODES * 64 * 2);
  unsigned short* tmp_n = (unsigned short*)alloc((size_t)N_NODES * 64 * 2);
  float* hn    = (float*)alloc((size_t)N_NODES * HID * 4);
  float* accb  = (float*)alloc((size_t)N_NODES * HID * 4);  // also enc1 partial scratch
  float* Wc_p  = (float*)alloc(HID * HID * 4);
  float* Wc_n  = (float*)alloc(HID * HID * 4);
  float* bc    = (float*)alloc(HID * 4);

  // zero bin_cur + colmax in one shot (contiguous allocs; colmax monotone across stages)
  hipMemsetAsync(bin_cur, 0, 3328 + 512, stream);

  dim3 blk(256);
  const int NBLK_A = 2 * ((N_EDGES + 8191) / 8192);
  prep_kernel<<<17, blk, 0, stream>>>(W_pp, W_pos, W_pn, W_neg, b_pos, b_pp, b_neg, b_pn,
                                      Wc_p, Wc_n, bc, xq_p, xq_n);
  binA_kernel<<<NBLK_A, blk, 0, stream>>>(ep, en, bin_cur, recs_p, recs_n);
  fillC_kernel<<<2 * NB2, blk, 0, stream>>>(bin_cur, recs_p, recs_n,
                                            off_p, off_n, dinv_p, dinv_n, cs_p, cs_n);
  enc1_kernel<<<1024, blk, 0, stream>>>(x, W_enc, accb);
  enc2_kernel<<<1024, blk, 0, stream>>>(x, W_enc, b_enc, gamma, beta, accb, hbase, hn);

  const int NBLK_QB = (N_NODES * 64 / 8 + 255) / 256;
  for (int s = 0; s < 8; ++s){
    convA_kernel<<<1024, blk, 0, stream>>>(hn, Wc_p, Wc_n, dinv_p, dinv_n,
                                           tmp_p, tmp_n, colmax);
    convB_kernel<<<NBLK_QB, blk, 0, stream>>>(tmp_p, tmp_n, colmax, xq_p, xq_n);
    gatherrk_kernel<<<(N_NODES / 2 + 3) / 4, blk, 0, stream>>>(
        xq_p, xq_n, colmax, cs_p, off_p, dinv_p, cs_n, off_n, dinv_n,
        bc, gamma, beta, tvec, hbase, accb, hn, s & 3, (s < 7) ? 1 : 0);
  }
}

// Round 10
// 1145.543 us; speedup vs baseline: 1.4235x; 1.1675x over previous
//
#include <hip/hip_runtime.h>

#define N_NODES 50000
#define N_FEAT  128
#define HID     64
#define N_EDGES 1600000
#define LN_EPS  1e-5f
#define NB2     400          // bins per side
#define BW2     125          // nodes per bin (400*125 = 50000)
#define CAP2    5120u        // per-bin record capacity (mean 4000, +17 sigma)

typedef unsigned int uint;

__device__ __forceinline__ float bcastf(float v, int l){
  return __uint_as_float(__builtin_amdgcn_readlane(__float_as_uint(v), l));
}
__device__ __forceinline__ unsigned short f2bf(float f){
  unsigned u = __float_as_uint(f);
  unsigned r = (u + 0x7fff + ((u >> 16) & 1)) >> 16;
  return (unsigned short)r;
}
__device__ __forceinline__ float bf2f(unsigned short u){
  return __uint_as_float(((unsigned)u) << 16);
}
// packed u16-pair accumulate: 1 VALU/element. Each uint holds two per-feature sums
// (no carry crossing: <=9 rows/group * 255 = 2295 << 65535). Bias-128 corrected later.
__device__ __forceinline__ void accp(uint* a, uint2 v){
  a[0] += __builtin_amdgcn_perm(0u, v.x, 0x0c010c00u);  // (f0, f1) as u16 halves
  a[1] += __builtin_amdgcn_perm(0u, v.x, 0x0c030c02u);  // (f2, f3)
  a[2] += __builtin_amdgcn_perm(0u, v.y, 0x0c010c00u);  // (f4, f5)
  a[3] += __builtin_amdgcn_perm(0u, v.y, 0x0c030c02u);  // (f6, f7)
}
// float u8 accumulate (slow path, deg > 64 only — avoids packed overflow concerns)
__device__ __forceinline__ void accu8(float* a, uint2 v){
  a[0] += (float)( v.x         & 0xffu);
  a[1] += (float)((v.x >> 8)   & 0xffu);
  a[2] += (float)((v.x >> 16)  & 0xffu);
  a[3] += (float)( v.x >> 24         );
  a[4] += (float)( v.y         & 0xffu);
  a[5] += (float)((v.y >> 8)   & 0xffu);
  a[6] += (float)((v.y >> 16)  & 0xffu);
  a[7] += (float)( v.y >> 24         );
}

// ---------------- precompute: Wc = Wpsi @ W, bc = combined bias, pad rows = 128 ---------
__global__ void prep_kernel(const float* __restrict__ Wpp, const float* __restrict__ Wp,
                            const float* __restrict__ Wpn, const float* __restrict__ Wn,
                            const float* __restrict__ bp, const float* __restrict__ bpp,
                            const float* __restrict__ bn, const float* __restrict__ bpn,
                            float* __restrict__ Wc_p, float* __restrict__ Wc_n,
                            float* __restrict__ bc,
                            unsigned char* __restrict__ xq_p, unsigned char* __restrict__ xq_n){
  int idx = blockIdx.x * blockDim.x + threadIdx.x;
  if (idx < 4096){
    int j = idx >> 6, k = idx & 63;
    float sp = 0.f, sn = 0.f;
    for (int m = 0; m < 64; ++m){
      sp += Wpp[j * 64 + m] * Wp[m * 64 + k];
      sn += Wpn[j * 64 + m] * Wn[m * 64 + k];
    }
    Wc_p[idx] = sp; Wc_n[idx] = sn;
  } else if (idx < 4160){
    int j = idx - 4096;
    float s = bpp[j] + bpn[j];
    for (int m = 0; m < 64; ++m) s += Wpp[j * 64 + m] * bp[m] + Wpn[j * 64 + m] * bn[m];
    bc[j] = s;
  } else if (idx < 4224){
    // pad row decodes to exactly 0: byte 128 with bias-128 correction
    xq_p[(size_t)N_NODES * 64 + (idx - 4160)] = 128;
    xq_n[(size_t)N_NODES * 64 + (idx - 4160)] = 128;
  }
}

// ---------------- phase A: bin edges by dst range (400 bins/side) ----------------
__global__ __launch_bounds__(256) void binA_kernel(
    const int* __restrict__ ep, const int* __restrict__ en,
    uint* __restrict__ bin_cur, uint* __restrict__ recs_p, uint* __restrict__ recs_n){
  __shared__ uint sh[8192];
  __shared__ uint cnt2[NB2], gb2[NB2], rnk2[NB2];
  const int NBLK = (N_EDGES + 8191) / 8192;
  int bid = blockIdx.x;
  int side = bid >= NBLK;
  const int* e = side ? en : ep;
  uint* recs = side ? recs_n : recs_p;
  uint* bcur = bin_cur + side * NB2;
  int cbase = (side ? bid - NBLK : bid) * 8192;
  int tid = threadIdx.x;
  for (int i = tid; i < NB2; i += 256){ cnt2[i] = 0; rnk2[i] = 0; }
  __syncthreads();
  for (int i = tid; i < 8192; i += 256){
    int t = cbase + i;
    uint r = 0xFFFFFFFFu;
    if (t < N_EDGES){
      uint s = (uint)e[t], d = (uint)e[N_EDGES + t];
      r = (d << 16) | s;
      atomicAdd(&cnt2[d / BW2], 1u);
    }
    sh[i] = r;
  }
  __syncthreads();
  for (int i = tid; i < NB2; i += 256) gb2[i] = atomicAdd(&bcur[i], cnt2[i]);
  __syncthreads();
  for (int i = tid; i < 8192; i += 256){
    uint r = sh[i];
    if (r != 0xFFFFFFFFu){
      uint b = (r >> 16) / BW2;
      uint pos = gb2[b] + atomicAdd(&rnk2[b], 1u);
      recs[b * CAP2 + pos] = r;
    }
  }
}

// -------- LDS counting sort per bin: dinv, off (global CSR offsets), cs (coalesced) ------
__global__ __launch_bounds__(256) void fillC_kernel(
    const uint* __restrict__ bin_cur,
    const uint* __restrict__ recs_p, const uint* __restrict__ recs_n,
    int* __restrict__ off_p, int* __restrict__ off_n,
    float* __restrict__ dinv_p, float* __restrict__ dinv_n,
    unsigned short* __restrict__ cs_p, unsigned short* __restrict__ cs_n){
  __shared__ int hist[128];
  __shared__ int curx[128];
  __shared__ unsigned short staged[CAP2];
  __shared__ uint base_s;
  int bid = blockIdx.x;
  int side = bid >= NB2; int b = side ? bid - NB2 : bid;
  const uint* recs = (side ? recs_n : recs_p) + (size_t)b * CAP2;
  int* off = side ? off_n : off_p;
  float* dinv = side ? dinv_n : dinv_p;
  unsigned short* cs = side ? cs_n : cs_p;
  int tid = threadIdx.x, lane = tid & 63, wid = tid >> 6;
  int nodebase = b * BW2;
  if (tid < 128) hist[tid] = 0;
  __syncthreads();
  uint n = bin_cur[side * NB2 + b];
  if (wid == 1){                        // bin's global output base
    uint s = 0;
    for (int k = lane; k < b; k += 64) s += bin_cur[side * NB2 + k];
    #pragma unroll
    for (int d = 1; d < 64; d <<= 1) s += __shfl_xor(s, d);
    if (lane == 0) base_s = s;
  }
  for (uint i = tid; i < n; i += 256)
    atomicAdd(&hist[(recs[i] >> 16) - nodebase], 1);
  __syncthreads();
  if (tid < BW2)
    dinv[nodebase + tid] = rsqrtf((float)(hist[tid] + 1));
  if (wid == 0){                        // exclusive scan hist -> curx
    int carry = 0;
    #pragma unroll
    for (int base = 0; base < BW2; base += 64){
      int idx = base + lane;
      int v = (idx < BW2) ? hist[idx] : 0;
      int x = v;
      #pragma unroll
      for (int d = 1; d < 64; d <<= 1){
        int y = __shfl_up(x, d);
        if (lane >= d) x += y;
      }
      if (idx < BW2) curx[idx] = carry + x - v;
      int tot = __shfl(x, 63);
      carry = carry + tot;
    }
  }
  __syncthreads();
  if (tid < BW2) off[nodebase + tid] = (int)base_s + curx[tid];
  if (b == NB2 - 1 && tid == 0) off[N_NODES] = (int)(base_s + n);
  __syncthreads();
  for (uint i = tid; i < n; i += 256){
    uint r = recs[i];
    int d = (int)(r >> 16) - nodebase;
    int p = atomicAdd(&curx[d], 1);
    staged[p] = (unsigned short)(r & 0xFFFFu);
  }
  __syncthreads();
  uint base = base_s;
  for (uint i = tid; i < n; i += 256) cs[base + i] = staged[i];
}

// ---- enc pass 1: part = x[:, 0:64] @ Wenc[:, 0:64]^T  (64 weight VGPRs per lane) -------
// R7/R8 lesson: a 128-float per-lane array gets left in scratch by the allocator
// (VGPR_Count=84, dur 99us, VALUBusy 17%). Keep per-lane weight arrays <= 64 floats.
__global__ __launch_bounds__(256) void enc1_kernel(
    const float* __restrict__ x, const float* __restrict__ Wenc,
    float* __restrict__ part){
  int lane = threadIdx.x & 63, wid = threadIdx.x >> 6;
  float we[64];
  const float* wr = Wenc + lane * N_FEAT;
  #pragma unroll
  for (int k4 = 0; k4 < 16; ++k4){
    float4 v = *(const float4*)(wr + 4 * k4);
    we[4*k4] = v.x; we[4*k4+1] = v.y; we[4*k4+2] = v.z; we[4*k4+3] = v.w;
  }
  int gw = blockIdx.x * 4 + wid, nw = gridDim.x * 4;
  for (int p = gw; p < N_NODES / 2; p += nw){
    int n0 = 2 * p, n1 = n0 + 1;
    float xa0 = x[(size_t)n0 * N_FEAT + lane];
    float xa1 = x[(size_t)n1 * N_FEAT + lane];
    float h0 = 0.f, h1 = 0.f;
    #pragma unroll
    for (int k = 0; k < 64; ++k){
      h0 += bcastf(xa0, k) * we[k];
      h1 += bcastf(xa1, k) * we[k];
    }
    part[n0 * HID + lane] = h0;
    part[n1 * HID + lane] = h1;
  }
}

// ---- enc pass 2: h = part + x[:, 64:128] @ Wenc[:, 64:128]^T + b; LN -> hbase, hn ------
__global__ __launch_bounds__(256) void enc2_kernel(
    const float* __restrict__ x, const float* __restrict__ Wenc, const float* __restrict__ benc,
    const float* __restrict__ gamma, const float* __restrict__ beta,
    const float* __restrict__ part,
    float* __restrict__ hbase, float* __restrict__ hn){
  int lane = threadIdx.x & 63, wid = threadIdx.x >> 6;
  float we[64];
  const float* wr = Wenc + lane * N_FEAT + 64;
  #pragma unroll
  for (int k4 = 0; k4 < 16; ++k4){
    float4 v = *(const float4*)(wr + 4 * k4);
    we[4*k4] = v.x; we[4*k4+1] = v.y; we[4*k4+2] = v.z; we[4*k4+3] = v.w;
  }
  float bv = benc[lane], g = gamma[lane], bt = beta[lane];
  int gw = blockIdx.x * 4 + wid, nw = gridDim.x * 4;
  for (int p = gw; p < N_NODES / 2; p += nw){
    int n0 = 2 * p, n1 = n0 + 1;
    float xb0 = x[(size_t)n0 * N_FEAT + 64 + lane];
    float xb1 = x[(size_t)n1 * N_FEAT + 64 + lane];
    float h0 = bv + part[n0 * HID + lane];
    float h1 = bv + part[n1 * HID + lane];
    #pragma unroll
    for (int k = 0; k < 64; ++k){
      h0 += bcastf(xb0, k) * we[k];
      h1 += bcastf(xb1, k) * we[k];
    }
    hbase[n0 * HID + lane] = h0;
    hbase[n1 * HID + lane] = h1;
    float s0 = h0, q0 = h0 * h0, s1 = h1, q1 = h1 * h1;
    #pragma unroll
    for (int d = 1; d < 64; d <<= 1){
      s0 += __shfl_xor(s0, d); q0 += __shfl_xor(q0, d);
      s1 += __shfl_xor(s1, d); q1 += __shfl_xor(q1, d);
    }
    float mu0 = s0 * (1.0f/64.0f), var0 = q0 * (1.0f/64.0f) - mu0 * mu0;
    float mu1 = s1 * (1.0f/64.0f), var1 = q1 * (1.0f/64.0f) - mu1 * mu1;
    hn[n0 * HID + lane] = (h0 - mu0) * rsqrtf(var0 + LN_EPS) * g + bt;
    hn[n1 * HID + lane] = (h1 - mu1) * rsqrtf(var1 + LN_EPS) * g + bt;
  }
}

// -------- convA (measure): side-split GEMV -> bf16 tmp + colmax (refresh stages) --------
// Side split keeps per-lane weight array at 64 floats (R7/R8: 128 spills at VGPR=84).
__global__ __launch_bounds__(256) void convA_kernel(
    const float* __restrict__ hn, const float* __restrict__ Wc_p, const float* __restrict__ Wc_n,
    const float* __restrict__ dinv_p, const float* __restrict__ dinv_n,
    unsigned short* __restrict__ tmp_p, unsigned short* __restrict__ tmp_n,
    uint* __restrict__ colmax){
  int lane = threadIdx.x & 63, wid = threadIdx.x >> 6;
  int side = wid & 1;                 // waves 0,2: pos; waves 1,3: neg
  const float* Wc   = side ? Wc_n   : Wc_p;
  const float* dinv = side ? dinv_n : dinv_p;
  unsigned short* tmp = side ? tmp_n : tmp_p;
  float w[64];
  const float* wr = Wc + lane * HID;
  #pragma unroll
  for (int k4 = 0; k4 < 16; ++k4){
    float4 a = *(const float4*)(wr + 4 * k4);
    w[4*k4] = a.x; w[4*k4+1] = a.y; w[4*k4+2] = a.z; w[4*k4+3] = a.w;
  }
  float m = 0.f;                      // lane == feature: colmax needs no cross-lane reduce
  int gw = blockIdx.x * 2 + (wid >> 1), nw = gridDim.x * 2;
  for (int p = gw; p < N_NODES / 2; p += nw){
    int n0 = 2 * p, n1 = n0 + 1;
    float h0 = hn[n0 * HID + lane], h1 = hn[n1 * HID + lane];
    float a0 = 0.f, a1 = 0.f;
    #pragma unroll
    for (int k = 0; k < 64; ++k){
      a0 += bcastf(h0, k) * w[k];
      a1 += bcastf(h1, k) * w[k];
    }
    a0 *= dinv[n0]; a1 *= dinv[n1];
    tmp[(size_t)n0 * 64 + lane] = f2bf(a0);
    tmp[(size_t)n1 * 64 + lane] = f2bf(a1);
    m = fmaxf(m, fmaxf(fabsf(a0), fabsf(a1)));
  }
  // 1.06: bf16-roundup (1.008) + cross-stage drift headroom (colmax frozen for 3 stages)
  m *= 1.06f;
  atomicMax(&colmax[side * 64 + lane], __float_as_uint(m));
}

// -------- convAQ (fused): GEMV + direct u8 quantize with frozen colmax ------------------
__global__ __launch_bounds__(256) void convAQ_kernel(
    const float* __restrict__ hn, const float* __restrict__ Wc_p, const float* __restrict__ Wc_n,
    const float* __restrict__ dinv_p, const float* __restrict__ dinv_n,
    const uint* __restrict__ colmax,
    unsigned char* __restrict__ xq_p, unsigned char* __restrict__ xq_n){
  int lane = threadIdx.x & 63, wid = threadIdx.x >> 6;
  int side = wid & 1;
  const float* Wc   = side ? Wc_n   : Wc_p;
  const float* dinv = side ? dinv_n : dinv_p;
  unsigned char* xq = side ? xq_n : xq_p;
  float w[64];
  const float* wr = Wc + lane * HID;
  #pragma unroll
  for (int k4 = 0; k4 < 16; ++k4){
    float4 a = *(const float4*)(wr + 4 * k4);
    w[4*k4] = a.x; w[4*k4+1] = a.y; w[4*k4+2] = a.z; w[4*k4+3] = a.w;
  }
  float cm = __uint_as_float(colmax[side * 64 + lane]);
  float inv = (cm > 0.f) ? 127.0f / cm : 0.f;
  int gw = blockIdx.x * 2 + (wid >> 1), nw = gridDim.x * 2;
  for (int p = gw; p < N_NODES / 2; p += nw){
    int n0 = 2 * p, n1 = n0 + 1;
    float h0 = hn[n0 * HID + lane], h1 = hn[n1 * HID + lane];
    float a0 = 0.f, a1 = 0.f;
    #pragma unroll
    for (int k = 0; k < 64; ++k){
      a0 += bcastf(h0, k) * w[k];
      a1 += bcastf(h1, k) * w[k];
    }
    a0 *= dinv[n0]; a1 *= dinv[n1];
    int q0 = (int)rintf(a0 * inv); q0 = q0 > 127 ? 127 : (q0 < -127 ? -127 : q0);
    int q1 = (int)rintf(a1 * inv); q1 = q1 > 127 ? 127 : (q1 < -127 ? -127 : q1);
    xq[(size_t)n0 * 64 + lane] = (unsigned char)(q0 + 128);
    xq[(size_t)n1 * 64 + lane] = (unsigned char)(q1 + 128);
  }
}

// -------- convB: quantize bf16 temp -> u8 with column scales (refresh stages only) ------
__global__ __launch_bounds__(256) void convB_kernel(
    const unsigned short* __restrict__ tmp_p, const unsigned short* __restrict__ tmp_n,
    const uint* __restrict__ colmax,
    unsigned char* __restrict__ xq_p, unsigned char* __restrict__ xq_n){
  int idx8 = blockIdx.x * 256 + threadIdx.x;        // 8 elems per thread
  if (idx8 >= (N_NODES * 64) / 8) return;
  int base = idx8 * 8;
  int f0 = base & 63;
  #pragma unroll
  for (int side = 0; side < 2; ++side){
    const unsigned short* tmp = side ? tmp_n : tmp_p;
    unsigned char* xq = side ? xq_n : xq_p;
    const uint* cm = colmax + side * 64;
    uint4 v = *(const uint4*)(tmp + base);
    unsigned short e[8] = {(unsigned short)(v.x & 0xffff), (unsigned short)(v.x >> 16),
                           (unsigned short)(v.y & 0xffff), (unsigned short)(v.y >> 16),
                           (unsigned short)(v.z & 0xffff), (unsigned short)(v.z >> 16),
                           (unsigned short)(v.w & 0xffff), (unsigned short)(v.w >> 16)};
    uint out[8];
    #pragma unroll
    for (int i = 0; i < 8; ++i){
      float cmv = __uint_as_float(cm[f0 + i]);
      float inv = (cmv > 0.f) ? 127.0f / cmv : 0.f;
      int q = (int)rintf(bf2f(e[i]) * inv);
      q = q > 127 ? 127 : (q < -127 ? -127 : q);
      out[i] = (uint)(q + 128);
    }
    uint2 w2;
    w2.x = out[0] | (out[1] << 8) | (out[2] << 16) | (out[3] << 24);
    w2.y = out[4] | (out[5] << 8) | (out[6] << 16) | (out[7] << 24);
    *(uint2*)(xq + base) = w2;
  }
}

// ---------------- slow-path accumulate (deg > 64): float, overflow-safe ------------------
__device__ __forceinline__ void gather_side_acc(
    const unsigned char* __restrict__ xq, const unsigned short* __restrict__ cs,
    int s0, int s1, int g, int j8, int lane, float* acc, int& nr){
  for (int base = s0; base < s1; base += 64){
    int jj = base + lane;
    int si = (jj < s1) ? (int)cs[jj] : N_NODES;
    int cnt = min(64, s1 - base);
    int nt = (cnt + 7) >> 3;
    for (int t = 0; t < nt; ++t){
      int r = __shfl(si, 8 * t + g);
      accu8(acc, *(const uint2*)(xq + (size_t)r * 64 + j8));
      nr += 1;
    }
  }
}

// ------ gather both sides, 2 nodes/wave, packed-u16 decode + RK4 + LN (fused) ------------
__global__ __launch_bounds__(256) void gatherrk_kernel(
    const unsigned char* __restrict__ xq_p, const unsigned char* __restrict__ xq_n,
    const uint* __restrict__ colmax,
    const unsigned short* __restrict__ cs_p, const int* __restrict__ off_p,
    const float* __restrict__ dinv_p,
    const unsigned short* __restrict__ cs_n, const int* __restrict__ off_n,
    const float* __restrict__ dinv_n,
    const float* __restrict__ bc, const float* __restrict__ gamma, const float* __restrict__ beta,
    const float* __restrict__ tvec,
    float* __restrict__ hbase, float* __restrict__ acc, float* __restrict__ hn,
    int st, int emit){
  int lane = threadIdx.x & 63, wid = threadIdx.x >> 6;
  int pair = blockIdx.x * 4 + wid;
  int nA = 2 * pair, nB = nA + 1;
  if (nA >= N_NODES) return;
  int g = lane >> 3, j = lane & 7, j8 = 8 * j, rowoff = j8;

  // column decode scales for this lane's 8 features
  float scolp[8], scoln[8];
  {
    float4 c0 = *(const float4*)((const float*)colmax + j8);
    float4 c1 = *(const float4*)((const float*)colmax + j8 + 4);
    float4 c2 = *(const float4*)((const float*)colmax + 64 + j8);
    float4 c3 = *(const float4*)((const float*)colmax + 64 + j8 + 4);
    const float r127 = 1.0f / 127.0f;
    scolp[0]=c0.x*r127; scolp[1]=c0.y*r127; scolp[2]=c0.z*r127; scolp[3]=c0.w*r127;
    scolp[4]=c1.x*r127; scolp[5]=c1.y*r127; scolp[6]=c1.z*r127; scolp[7]=c1.w*r127;
    scoln[0]=c2.x*r127; scoln[1]=c2.y*r127; scoln[2]=c2.z*r127; scoln[3]=c2.w*r127;
    scoln[4]=c3.x*r127; scoln[5]=c3.y*r127; scoln[6]=c3.z*r127; scoln[7]=c3.w*r127;
  }

  int pA0 = off_p[nA], pA1 = off_p[nA + 1], pB1 = off_p[nB + 1];
  int qA0 = off_n[nA], qA1 = off_n[nA + 1], qB1 = off_n[nB + 1];
  int dPA = pA1 - pA0, dPB = pB1 - pA1, dNA = qA1 - qA0, dNB = qB1 - qA1;

  float fPA[8], fPB[8], fNA[8], fNB[8];     // per-group sums (u8-biased units)
  int nrPA = 1, nrPB = 1, nrNA = 1, nrNB = 1;   // self rows

  if (dPA <= 64 && dPB <= 64 && dNA <= 64 && dNB <= 64){
    uint pPA[4] = {0,0,0,0}, pPB[4] = {0,0,0,0};
    uint pNA[4] = {0,0,0,0}, pNB[4] = {0,0,0,0};
    {   // self rows (group 0 real, other groups hit 128-pad row -> decodes 0 with count)
      int rA = (g == 0) ? nA : N_NODES;
      int rB = (g == 0) ? nB : N_NODES;
      accp(pPA, *(const uint2*)(xq_p + (size_t)rA * 64 + j8));
      accp(pPB, *(const uint2*)(xq_p + (size_t)rB * 64 + j8));
      accp(pNA, *(const uint2*)(xq_n + (size_t)rA * 64 + j8));
      accp(pNB, *(const uint2*)(xq_n + (size_t)rB * 64 + j8));
    }
    int siPA = (lane < dPA) ? (int)cs_p[pA0 + lane] : N_NODES;
    int siPB = (lane < dPB) ? (int)cs_p[pA1 + lane] : N_NODES;
    int siNA = (lane < dNA) ? (int)cs_n[qA0 + lane] : N_NODES;
    int siNB = (lane < dNB) ? (int)cs_n[qA1 + lane] : N_NODES;
    int dP = dPA > dPB ? dPA : dPB;
    int dN = dNA > dNB ? dNA : dNB;
    int ntP = (dP + 7) >> 3, ntN = (dN + 7) >> 3;
    for (int t = 0; t < ntP; t += 2){
      int gi0 = 8 * t + g, gi1 = gi0 + 8;
      int rA0 = __shfl(siPA, gi0), rB0 = __shfl(siPB, gi0);
      int rA1 = __shfl(siPA, gi1), rB1 = __shfl(siPB, gi1);
      uint2 vA0 = *(const uint2*)(xq_p + (size_t)rA0 * 64 + j8);
      uint2 vB0 = *(const uint2*)(xq_p + (size_t)rB0 * 64 + j8);
      uint2 vA1 = *(const uint2*)(xq_p + (size_t)rA1 * 64 + j8);
      uint2 vB1 = *(const uint2*)(xq_p + (size_t)rB1 * 64 + j8);
      accp(pPA, vA0); accp(pPB, vB0); accp(pPA, vA1); accp(pPB, vB1);
      nrPA += 2; nrPB += 2;
    }
    for (int t = 0; t < ntN; t += 2){
      int gi0 = 8 * t + g, gi1 = gi0 + 8;
      int rA0 = __shfl(siNA, gi0), rB0 = __shfl(siNB, gi0);
      int rA1 = __shfl(siNA, gi1), rB1 = __shfl(siNB, gi1);
      uint2 vA0 = *(const uint2*)(xq_n + (size_t)rA0 * 64 + j8);
      uint2 vB0 = *(const uint2*)(xq_n + (size_t)rB0 * 64 + j8);
      uint2 vA1 = *(const uint2*)(xq_n + (size_t)rA1 * 64 + j8);
      uint2 vB1 = *(const uint2*)(xq_n + (size_t)rB1 * 64 + j8);
      accp(pNA, vA0); accp(pNB, vB0); accp(pNA, vA1); accp(pNB, vB1);
      nrNA += 2; nrNB += 2;
    }
    #pragma unroll
    for (int i = 0; i < 4; ++i){
      fPA[2*i] = (float)(pPA[i] & 0xFFFFu); fPA[2*i+1] = (float)(pPA[i] >> 16);
      fPB[2*i] = (float)(pPB[i] & 0xFFFFu); fPB[2*i+1] = (float)(pPB[i] >> 16);
      fNA[2*i] = (float)(pNA[i] & 0xFFFFu); fNA[2*i+1] = (float)(pNA[i] >> 16);
      fNB[2*i] = (float)(pNB[i] & 0xFFFFu); fNB[2*i+1] = (float)(pNB[i] >> 16);
    }
  } else {
    #pragma unroll
    for (int i = 0; i < 8; ++i){ fPA[i] = 0.f; fPB[i] = 0.f; fNA[i] = 0.f; fNB[i] = 0.f; }
    int rA = (g == 0) ? nA : N_NODES;
    int rB = (g == 0) ? nB : N_NODES;
    accu8(fPA, *(const uint2*)(xq_p + (size_t)rA * 64 + j8));
    accu8(fPB, *(const uint2*)(xq_p + (size_t)rB * 64 + j8));
    accu8(fNA, *(const uint2*)(xq_n + (size_t)rA * 64 + j8));
    accu8(fNB, *(const uint2*)(xq_n + (size_t)rB * 64 + j8));
    gather_side_acc(xq_p, cs_p, pA0, pA1, g, j8, lane, fPA, nrPA);
    gather_side_acc(xq_p, cs_p, pA1, pB1, g, j8, lane, fPB, nrPB);
    gather_side_acc(xq_n, cs_n, qA0, qA1, g, j8, lane, fNA, nrNA);
    gather_side_acc(xq_n, cs_n, qA1, qB1, g, j8, lane, fNB, nrNB);
  }
  // cross-group reduce; bias correction (128 per row, 8 groups) + column scale
  #pragma unroll
  for (int i = 0; i < 8; ++i){
    float a = fPA[i]; a += __shfl_xor(a, 8); a += __shfl_xor(a, 16); a += __shfl_xor(a, 32);
    fPA[i] = scolp[i] * (a - 1024.f * (float)nrPA);
    float b = fPB[i]; b += __shfl_xor(b, 8); b += __shfl_xor(b, 16); b += __shfl_xor(b, 32);
    fPB[i] = scolp[i] * (b - 1024.f * (float)nrPB);
    float c = fNA[i]; c += __shfl_xor(c, 8); c += __shfl_xor(c, 16); c += __shfl_xor(c, 32);
    fNA[i] = scoln[i] * (c - 1024.f * (float)nrNA);
    float d = fNB[i]; d += __shfl_xor(d, 8); d += __shfl_xor(d, 16); d += __shfl_xor(d, 32);
    fNB[i] = scoln[i] * (d - 1024.f * (float)nrNB);
  }

  float dvpA = dinv_p[nA], dvnA = dinv_n[nA], dvpB = dinv_p[nB], dvnB = dinv_n[nB];
  float4 b0 = *(const float4*)(bc + rowoff);
  float4 b1 = *(const float4*)(bc + rowoff + 4);
  float bcv[8] = {b0.x, b0.y, b0.z, b0.w, b1.x, b1.y, b1.z, b1.w};

  size_t ixA = (size_t)nA * HID + rowoff, ixB = (size_t)nB * HID + rowoff;
  float4 hA0 = *(const float4*)(hbase + ixA), hA1 = *(const float4*)(hbase + ixA + 4);
  float4 hB0 = *(const float4*)(hbase + ixB), hB1 = *(const float4*)(hbase + ixB + 4);
  float hbA[8] = {hA0.x,hA0.y,hA0.z,hA0.w,hA1.x,hA1.y,hA1.z,hA1.w};
  float hbB[8] = {hB0.x,hB0.y,hB0.z,hB0.w,hB1.x,hB1.y,hB1.z,hB1.w};
  float avA[8], avB[8];
  if (st != 0){
    float4 aA0 = *(const float4*)(acc + ixA), aA1 = *(const float4*)(acc + ixA + 4);
    float4 aB0 = *(const float4*)(acc + ixB), aB1 = *(const float4*)(acc + ixB + 4);
    avA[0]=aA0.x; avA[1]=aA0.y; avA[2]=aA0.z; avA[3]=aA0.w;
    avA[4]=aA1.x; avA[5]=aA1.y; avA[6]=aA1.z; avA[7]=aA1.w;
    avB[0]=aB0.x; avB[1]=aB0.y; avB[2]=aB0.z; avB[3]=aB0.w;
    avB[4]=aB1.x; avB[5]=aB1.y; avB[6]=aB1.z; avB[7]=aB1.w;
  }
  float dt = (tvec[1] - tvec[0]) * 0.5f;
  float hvA[8], hvB[8];
  #pragma unroll
  for (int i = 0; i < 8; ++i){
    float dA = dvpA * fPA[i] + dvnA * fNA[i] + bcv[i];
    float dB = dvpB * fPB[i] + dvnB * fNB[i] + bcv[i];
    dA = fminf(fmaxf(dA, -50.f), 50.f);
    dB = fminf(fmaxf(dB, -50.f), 50.f);
    if (st == 0){
      avA[i] = dA; avB[i] = dB;
      hvA[i] = hbA[i] + 0.5f * dt * dA; hvB[i] = hbB[i] + 0.5f * dt * dB;
    } else if (st == 1){
      avA[i] += 2.0f * dA; avB[i] += 2.0f * dB;
      hvA[i] = hbA[i] + 0.5f * dt * dA; hvB[i] = hbB[i] + 0.5f * dt * dB;
    } else if (st == 2){
      avA[i] += 2.0f * dA; avB[i] += 2.0f * dB;
      hvA[i] = hbA[i] + dt * dA; hvB[i] = hbB[i] + dt * dB;
    } else {
      hvA[i] = hbA[i] + (dt * (1.0f/6.0f)) * (avA[i] + dA);
      hvB[i] = hbB[i] + (dt * (1.0f/6.0f)) * (avB[i] + dB);
    }
  }
  if (st < 3){
    if (g == 0){
      float4 o0 = {avA[0],avA[1],avA[2],avA[3]}, o1 = {avA[4],avA[5],avA[6],avA[7]};
      *(float4*)(acc + ixA) = o0; *(float4*)(acc + ixA + 4) = o1;
    } else if (g == 1){
      float4 o0 = {avB[0],avB[1],avB[2],avB[3]}, o1 = {avB[4],avB[5],avB[6],avB[7]};
      *(float4*)(acc + ixB) = o0; *(float4*)(acc + ixB + 4) = o1;
    }
  } else {
    if (g == 0){
      float4 o0 = {hvA[0],hvA[1],hvA[2],hvA[3]}, o1 = {hvA[4],hvA[5],hvA[6],hvA[7]};
      *(float4*)(hbase + ixA) = o0; *(float4*)(hbase + ixA + 4) = o1;
    } else if (g == 1){
      float4 o0 = {hvB[0],hvB[1],hvB[2],hvB[3]}, o1 = {hvB[4],hvB[5],hvB[6],hvB[7]};
      *(float4*)(hbase + ixB) = o0; *(float4*)(hbase + ixB + 4) = o1;
    }
  }
  if (emit){
    float sA = 0.f, qA = 0.f, sB = 0.f, qB = 0.f;
    #pragma unroll
    for (int i = 0; i < 8; ++i){
      sA += hvA[i]; qA += hvA[i] * hvA[i];
      sB += hvB[i]; qB += hvB[i] * hvB[i];
    }
    sA += __shfl_xor(sA, 1); qA += __shfl_xor(qA, 1);
    sA += __shfl_xor(sA, 2); qA += __shfl_xor(qA, 2);
    sA += __shfl_xor(sA, 4); qA += __shfl_xor(qA, 4);
    sB += __shfl_xor(sB, 1); qB += __shfl_xor(qB, 1);
    sB += __shfl_xor(sB, 2); qB += __shfl_xor(qB, 2);
    sB += __shfl_xor(sB, 4); qB += __shfl_xor(qB, 4);
    float muA = sA * (1.0f/64.0f), varA = qA * (1.0f/64.0f) - muA * muA;
    float muB = sB * (1.0f/64.0f), varB = qB * (1.0f/64.0f) - muB * muB;
    float rsA = rsqrtf(varA + LN_EPS), rsB = rsqrtf(varB + LN_EPS);
    float4 g0 = *(const float4*)(gamma + rowoff);
    float4 g1 = *(const float4*)(gamma + rowoff + 4);
    float4 t0 = *(const float4*)(beta + rowoff);
    float4 t1 = *(const float4*)(beta + rowoff + 4);
    float gm[8] = {g0.x,g0.y,g0.z,g0.w,g1.x,g1.y,g1.z,g1.w};
    float bt[8] = {t0.x,t0.y,t0.z,t0.w,t1.x,t1.y,t1.z,t1.w};
    if (g == 0){
      float4 o0, o1;
      o0.x=(hvA[0]-muA)*rsA*gm[0]+bt[0]; o0.y=(hvA[1]-muA)*rsA*gm[1]+bt[1];
      o0.z=(hvA[2]-muA)*rsA*gm[2]+bt[2]; o0.w=(hvA[3]-muA)*rsA*gm[3]+bt[3];
      o1.x=(hvA[4]-muA)*rsA*gm[4]+bt[4]; o1.y=(hvA[5]-muA)*rsA*gm[5]+bt[5];
      o1.z=(hvA[6]-muA)*rsA*gm[6]+bt[6]; o1.w=(hvA[7]-muA)*rsA*gm[7]+bt[7];
      *(float4*)(hn + ixA) = o0; *(float4*)(hn + ixA + 4) = o1;
    } else if (g == 1){
      float4 o0, o1;
      o0.x=(hvB[0]-muB)*rsB*gm[0]+bt[0]; o0.y=(hvB[1]-muB)*rsB*gm[1]+bt[1];
      o0.z=(hvB[2]-muB)*rsB*gm[2]+bt[2]; o0.w=(hvB[3]-muB)*rsB*gm[3]+bt[3];
      o1.x=(hvB[4]-muB)*rsB*gm[4]+bt[4]; o1.y=(hvB[5]-muB)*rsB*gm[5]+bt[5];
      o1.z=(hvB[6]-muB)*rsB*gm[6]+bt[6]; o1.w=(hvB[7]-muB)*rsB*gm[7]+bt[7];
      *(float4*)(hn + ixB) = o0; *(float4*)(hn + ixB + 4) = o1;
    }
  }
}

extern "C" void kernel_launch(void* const* d_in, const int* in_sizes, int n_in,
                              void* d_out, int out_size, void* d_ws, size_t ws_size,
                              hipStream_t stream){
  const float* x     = (const float*)d_in[0];
  const int*   ep    = (const int*)d_in[1];
  const int*   en    = (const int*)d_in[2];
  const float* tvec  = (const float*)d_in[3];
  const float* W_enc = (const float*)d_in[4];
  const float* b_enc = (const float*)d_in[5];
  const float* W_pos = (const float*)d_in[6];
  const float* b_pos = (const float*)d_in[7];
  const float* W_neg = (const float*)d_in[8];
  const float* b_neg = (const float*)d_in[9];
  const float* W_pp  = (const float*)d_in[10];
  const float* b_pp  = (const float*)d_in[11];
  const float* W_pn  = (const float*)d_in[12];
  const float* b_pn  = (const float*)d_in[13];
  const float* gamma = (const float*)d_in[14];
  const float* beta  = (const float*)d_in[15];
  float* hbase = (float*)d_out;

  char* w = (char*)d_ws;
  auto alloc = [&](size_t bytes) -> char* {
    char* p = w;
    w += (bytes + 255) & ~(size_t)255;
    return p;
  };
  uint*  bin_cur = (uint*)alloc(2 * NB2 * 4);          // 3200 -> padded 3328
  uint*  colmax  = (uint*)alloc(128 * 4);              // contiguous after bin_cur
  int*   off_p = (int*)alloc((N_NODES + 1) * 4);
  int*   off_n = (int*)alloc((N_NODES + 1) * 4);
  float* dinv_p= (float*)alloc(N_NODES * 4);
  float* dinv_n= (float*)alloc(N_NODES * 4);
  uint*  recs_p= (uint*)alloc((size_t)NB2 * CAP2 * 4);
  uint*  recs_n= (uint*)alloc((size_t)NB2 * CAP2 * 4);
  unsigned short* cs_p = (unsigned short*)alloc((size_t)N_EDGES * 2);
  unsigned short* cs_n = (unsigned short*)alloc((size_t)N_EDGES * 2);
  unsigned char* xq_p = (unsigned char*)alloc((size_t)(N_NODES + 1) * 64);
  unsigned char* xq_n = (unsigned char*)alloc((size_t)(N_NODES + 1) * 64);
  unsigned short* tmp_p = (unsigned short*)alloc((size_t)N_NODES * 64 * 2);
  unsigned short* tmp_n = (unsigned short*)alloc((size_t)N_NODES * 64 * 2);
  float* hn    = (float*)alloc((size_t)N_NODES * HID * 4);
  float* accb  = (float*)alloc((size_t)N_NODES * HID * 4);  // also enc1 partial scratch
  float* Wc_p  = (float*)alloc(HID * HID * 4);
  float* Wc_n  = (float*)alloc(HID * HID * 4);
  float* bc    = (float*)alloc(HID * 4);

  // zero bin_cur + colmax in one shot (contiguous allocs; colmax monotone across stages)
  hipMemsetAsync(bin_cur, 0, 3328 + 512, stream);

  dim3 blk(256);
  const int NBLK_A = 2 * ((N_EDGES + 8191) / 8192);
  prep_kernel<<<17, blk, 0, stream>>>(W_pp, W_pos, W_pn, W_neg, b_pos, b_pp, b_neg, b_pn,
                                      Wc_p, Wc_n, bc, xq_p, xq_n);
  binA_kernel<<<NBLK_A, blk, 0, stream>>>(ep, en, bin_cur, recs_p, recs_n);
  fillC_kernel<<<2 * NB2, blk, 0, stream>>>(bin_cur, recs_p, recs_n,
                                            off_p, off_n, dinv_p, dinv_n, cs_p, cs_n);
  enc1_kernel<<<1024, blk, 0, stream>>>(x, W_enc, accb);
  enc2_kernel<<<1024, blk, 0, stream>>>(x, W_enc, b_enc, gamma, beta, accb, hbase, hn);

  const int NBLK_QB = (N_NODES * 64 / 8 + 255) / 256;
  for (int s = 0; s < 8; ++s){
    if (s == 0 || s == 4){
      // refresh stages: measure colmax (monotone atomicMax) then quantize consistently
      convA_kernel<<<1024, blk, 0, stream>>>(hn, Wc_p, Wc_n, dinv_p, dinv_n,
                                             tmp_p, tmp_n, colmax);
      convB_kernel<<<NBLK_QB, blk, 0, stream>>>(tmp_p, tmp_n, colmax, xq_p, xq_n);
    } else {
      // fused: quantize with frozen colmax (clamped; 1.06 headroom baked in)
      convAQ_kernel<<<1024, blk, 0, stream>>>(hn, Wc_p, Wc_n, dinv_p, dinv_n,
                                              colmax, xq_p, xq_n);
    }
    gatherrk_kernel<<<(N_NODES / 2 + 3) / 4, blk, 0, stream>>>(
        xq_p, xq_n, colmax, cs_p, off_p, dinv_p, cs_n, off_n, dinv_n,
        bc, gamma, beta, tvec, hbase, accb, hn, s & 3, (s < 7) ? 1 : 0);
  }
}